// Round 2
// baseline (7287.738 us; speedup 1.0000x reference)
//
#include <hip/hip_runtime.h>
#include <cmath>

#define GN 2048
#define GB 16

// ---------------- reductions ----------------
__device__ __forceinline__ float wave_max(float v) {
#pragma unroll
    for (int o = 32; o > 0; o >>= 1) v = fmaxf(v, __shfl_xor(v, o, 64));
    return v;
}
__device__ __forceinline__ float wave_sum(float v) {
#pragma unroll
    for (int o = 32; o > 0; o >>= 1) v += __shfl_xor(v, o, 64);
    return v;
}
__device__ __forceinline__ float block_max(float v) {
    __shared__ float sm[4];
    v = wave_max(v);
    if ((threadIdx.x & 63) == 0) sm[threadIdx.x >> 6] = v;
    __syncthreads();
    v = fmaxf(fmaxf(sm[0], sm[1]), fmaxf(sm[2], sm[3]));
    __syncthreads();
    return v;
}
__device__ __forceinline__ float block_sum(float v) {
    __shared__ float sm[4];
    v = wave_sum(v);
    if ((threadIdx.x & 63) == 0) sm[threadIdx.x >> 6] = v;
    __syncthreads();
    v = sm[0] + sm[1] + sm[2] + sm[3];
    __syncthreads();
    return v;
}

// ---------------- posenc + conv1 + relu ----------------
// x [B,3,N] -> h1 [B,128,N]
__global__ __launch_bounds__(256) void posenc_conv1_k(
    const float* __restrict__ x, const float* __restrict__ w1,
    const float* __restrict__ b1, float* __restrict__ h1) {
    __shared__ float w[128 * 21];
    __shared__ float bb[128];
    for (int i = threadIdx.x; i < 128 * 21; i += 256) w[i] = w1[i];
    if (threadIdx.x < 128) bb[threadIdx.x] = b1[threadIdx.x];
    __syncthreads();
    int pos = blockIdx.x * 256 + threadIdx.x;  // b*N + n
    int b = pos >> 11, n = pos & (GN - 1);
    const float* xb = x + (long)b * 3 * GN + n;
    float t0 = xb[0], t1 = xb[GN], t2 = xb[2 * GN];
    float e[21];
    e[0] = t0; e[1] = t1; e[2] = t2;
    e[3] = sinf(t0); e[4] = sinf(t1); e[5] = sinf(t2);
    e[6] = cosf(t0); e[7] = cosf(t1); e[8] = cosf(t2);
    e[9] = sinf(2.f * t0); e[10] = sinf(2.f * t1); e[11] = sinf(2.f * t2);
    e[12] = cosf(2.f * t0); e[13] = cosf(2.f * t1); e[14] = cosf(2.f * t2);
    e[15] = sinf(4.f * t0); e[16] = sinf(4.f * t1); e[17] = sinf(4.f * t2);
    e[18] = cosf(4.f * t0); e[19] = cosf(4.f * t1); e[20] = cosf(4.f * t2);
    float* out = h1 + (long)b * 128 * GN + n;
    for (int o = 0; o < 128; ++o) {
        float s = bb[o];
        const float* wr = &w[o * 21];
#pragma unroll
        for (int c = 0; c < 21; ++c) s = fmaf(wr[c], e[c], s);
        out[(long)o * GN] = fmaxf(s, 0.f);
    }
}

// ---------------- generic tiled fp32 GEMM ----------------
// C[m,n] = sum_k Alog[m,k]*Blog[k,n] (+bias[m]) per batch z.
// TRANS_A: A stored [K,M] row-stride lda (access A[k*lda+m]); else [M,K] stride lda.
// TRANS_B: B stored [N,K] row-stride ldb (access B[n*ldb+k]); else [K,N] stride ldb.
// SUB (non-trans B only): B_eff = B - B2.
template <bool TRANS_A, bool TRANS_B, bool RELU, bool SUB>
__global__ __launch_bounds__(256) void gemm_k(
    const float* __restrict__ A, int lda, long long aBatch,
    const float* __restrict__ Bm, int ldb, long long bBatch,
    const float* __restrict__ B2,
    const float* __restrict__ bias, int biasBatch,
    float* __restrict__ C, int ldc, long long cBatch,
    int M, int Nn, int K) {
    const int bz = blockIdx.z;
    A += (long long)bz * aBatch;
    Bm += (long long)bz * bBatch;
    C += (long long)bz * cBatch;
    const float* B2p = SUB ? (B2 + (long long)bz * bBatch) : nullptr;
    const int m0 = blockIdx.y * 64;
    const int n0 = blockIdx.x * 64;
    const int tid = threadIdx.x;
    const int tx = tid & 15, ty = tid >> 4;

    __shared__ float As[16][65];
    __shared__ float Bs[16][65];

    float acc[4][4] = {};
    for (int k0 = 0; k0 < K; k0 += 16) {
        if (TRANS_A) {
            int kk = tid >> 4;            // 0..15
            int mm = (tid & 15) * 4;      // 0..60
            float4 v = *(const float4*)(A + (long)(k0 + kk) * lda + (m0 + mm));
            As[kk][mm + 0] = v.x; As[kk][mm + 1] = v.y;
            As[kk][mm + 2] = v.z; As[kk][mm + 3] = v.w;
        } else {
            int mm = tid >> 2;            // 0..63
            int kk = (tid & 3) * 4;       // 0..12
            float4 v = *(const float4*)(A + (long)(m0 + mm) * lda + (k0 + kk));
            As[kk + 0][mm] = v.x; As[kk + 1][mm] = v.y;
            As[kk + 2][mm] = v.z; As[kk + 3][mm] = v.w;
        }
        if (TRANS_B) {
            int nn = tid >> 2;
            int kk = (tid & 3) * 4;
            float4 v = *(const float4*)(Bm + (long)(n0 + nn) * ldb + (k0 + kk));
            Bs[kk + 0][nn] = v.x; Bs[kk + 1][nn] = v.y;
            Bs[kk + 2][nn] = v.z; Bs[kk + 3][nn] = v.w;
        } else {
            int kk = tid >> 4;
            int nn = (tid & 15) * 4;
            float4 v = *(const float4*)(Bm + (long)(k0 + kk) * ldb + (n0 + nn));
            if (SUB) {
                float4 w = *(const float4*)(B2p + (long)(k0 + kk) * ldb + (n0 + nn));
                v.x -= w.x; v.y -= w.y; v.z -= w.z; v.w -= w.w;
            }
            Bs[kk][nn + 0] = v.x; Bs[kk][nn + 1] = v.y;
            Bs[kk][nn + 2] = v.z; Bs[kk][nn + 3] = v.w;
        }
        __syncthreads();
#pragma unroll
        for (int kk = 0; kk < 16; ++kk) {
            float a0 = As[kk][ty * 4 + 0], a1 = As[kk][ty * 4 + 1];
            float a2 = As[kk][ty * 4 + 2], a3 = As[kk][ty * 4 + 3];
            float b0 = Bs[kk][tx * 4 + 0], b1 = Bs[kk][tx * 4 + 1];
            float b2 = Bs[kk][tx * 4 + 2], b3 = Bs[kk][tx * 4 + 3];
            acc[0][0] = fmaf(a0, b0, acc[0][0]); acc[0][1] = fmaf(a0, b1, acc[0][1]);
            acc[0][2] = fmaf(a0, b2, acc[0][2]); acc[0][3] = fmaf(a0, b3, acc[0][3]);
            acc[1][0] = fmaf(a1, b0, acc[1][0]); acc[1][1] = fmaf(a1, b1, acc[1][1]);
            acc[1][2] = fmaf(a1, b2, acc[1][2]); acc[1][3] = fmaf(a1, b3, acc[1][3]);
            acc[2][0] = fmaf(a2, b0, acc[2][0]); acc[2][1] = fmaf(a2, b1, acc[2][1]);
            acc[2][2] = fmaf(a2, b2, acc[2][2]); acc[2][3] = fmaf(a2, b3, acc[2][3]);
            acc[3][0] = fmaf(a3, b0, acc[3][0]); acc[3][1] = fmaf(a3, b1, acc[3][1]);
            acc[3][2] = fmaf(a3, b2, acc[3][2]); acc[3][3] = fmaf(a3, b3, acc[3][3]);
        }
        __syncthreads();
    }
#pragma unroll
    for (int i = 0; i < 4; ++i) {
        int m = m0 + ty * 4 + i;
        float bv = bias ? bias[(long)bz * biasBatch + m] : 0.f;
#pragma unroll
        for (int j = 0; j < 4; ++j) {
            float v = acc[i][j] + bv;
            if (RELU) v = fmaxf(v, 0.f);
            C[(long)m * ldc + (n0 + tx * 4 + j)] = v;
        }
    }
}

// ---------------- fused final conv + per-tile row max ----------------
// partial[(bz*M + m)*32 + blockIdx.x] = max_n_tile (w4@h3)[m,n]  (bias added)
__global__ __launch_bounds__(256) void gemm_max_k(
    const float* __restrict__ A, int lda,                 // w4 [M,K]
    const float* __restrict__ Bm, int ldb, long long bBatch,  // h3 [B,K,N]
    const float* __restrict__ bias,
    float* __restrict__ partial, int M, int K) {
    const int bz = blockIdx.z;
    Bm += (long long)bz * bBatch;
    const int m0 = blockIdx.y * 64;
    const int n0 = blockIdx.x * 64;
    const int tid = threadIdx.x;
    const int tx = tid & 15, ty = tid >> 4;

    __shared__ float As[16][65];
    __shared__ float Bs[16][65];

    float acc[4][4] = {};
    for (int k0 = 0; k0 < K; k0 += 16) {
        {
            int mm = tid >> 2;
            int kk = (tid & 3) * 4;
            float4 v = *(const float4*)(A + (long)(m0 + mm) * lda + (k0 + kk));
            As[kk + 0][mm] = v.x; As[kk + 1][mm] = v.y;
            As[kk + 2][mm] = v.z; As[kk + 3][mm] = v.w;
        }
        {
            int kk = tid >> 4;
            int nn = (tid & 15) * 4;
            float4 v = *(const float4*)(Bm + (long)(k0 + kk) * ldb + (n0 + nn));
            Bs[kk][nn + 0] = v.x; Bs[kk][nn + 1] = v.y;
            Bs[kk][nn + 2] = v.z; Bs[kk][nn + 3] = v.w;
        }
        __syncthreads();
#pragma unroll
        for (int kk = 0; kk < 16; ++kk) {
            float a0 = As[kk][ty * 4 + 0], a1 = As[kk][ty * 4 + 1];
            float a2 = As[kk][ty * 4 + 2], a3 = As[kk][ty * 4 + 3];
            float b0 = Bs[kk][tx * 4 + 0], b1 = Bs[kk][tx * 4 + 1];
            float b2 = Bs[kk][tx * 4 + 2], b3 = Bs[kk][tx * 4 + 3];
            acc[0][0] = fmaf(a0, b0, acc[0][0]); acc[0][1] = fmaf(a0, b1, acc[0][1]);
            acc[0][2] = fmaf(a0, b2, acc[0][2]); acc[0][3] = fmaf(a0, b3, acc[0][3]);
            acc[1][0] = fmaf(a1, b0, acc[1][0]); acc[1][1] = fmaf(a1, b1, acc[1][1]);
            acc[1][2] = fmaf(a1, b2, acc[1][2]); acc[1][3] = fmaf(a1, b3, acc[1][3]);
            acc[2][0] = fmaf(a2, b0, acc[2][0]); acc[2][1] = fmaf(a2, b1, acc[2][1]);
            acc[2][2] = fmaf(a2, b2, acc[2][2]); acc[2][3] = fmaf(a2, b3, acc[2][3]);
            acc[3][0] = fmaf(a3, b0, acc[3][0]); acc[3][1] = fmaf(a3, b1, acc[3][1]);
            acc[3][2] = fmaf(a3, b2, acc[3][2]); acc[3][3] = fmaf(a3, b3, acc[3][3]);
        }
        __syncthreads();
    }
#pragma unroll
    for (int i = 0; i < 4; ++i) {
        float v = fmaxf(fmaxf(acc[i][0], acc[i][1]), fmaxf(acc[i][2], acc[i][3]));
        // reduce across the 16 tx lanes (they share ty, contiguous within a wave)
#pragma unroll
        for (int o = 1; o < 16; o <<= 1) v = fmaxf(v, __shfl_xor(v, o, 64));
        if (tx == 0) {
            int m = m0 + ty * 4 + i;
            partial[(((long)bz * M + m) << 5) | blockIdx.x] = v + bias[m];
        }
    }
}

// out[i] = max over 32 partials
__global__ __launch_bounds__(256) void max_final_k(const float* __restrict__ partial,
                                                   float* __restrict__ out) {
    int i = blockIdx.x * 256 + threadIdx.x;  // 0 .. 16*1024
    const float* p = partial + ((long)i << 5);
    float m = p[0];
#pragma unroll
    for (int j = 1; j < 32; ++j) m = fmaxf(m, p[j]);
    out[i] = m;
}

// ---------------- max over n: g[b,c] = max_n h2[b,c,n] ----------------
__global__ __launch_bounds__(256) void maxn_k(const float* __restrict__ h2,
                                              float* __restrict__ g) {
    const float* p = h2 + (long)blockIdx.x * GN;
    float m = -1e30f;
    for (int i = threadIdx.x; i < GN; i += 256) m = fmaxf(m, p[i]);
    m = block_max(m);
    if (threadIdx.x == 0) g[blockIdx.x] = m;
}

// ---------------- cvec[b,o] = b3[o] + sum_c w3[o,256+c]*g[b,c] ----------------
__global__ __launch_bounds__(256) void cvec_k(const float* __restrict__ w3,
                                              const float* __restrict__ b3,
                                              const float* __restrict__ g,
                                              float* __restrict__ cvec) {
    int idx = blockIdx.x * 256 + threadIdx.x;  // b*512 + o
    int b = idx >> 9, o = idx & 511;
    const float* gb = g + b * 256;
    const float* wr = w3 + (long)o * 512 + 256;
    float s = b3[o];
    for (int c = 0; c < 256; ++c) s = fmaf(wr[c], gb[c], s);
    cvec[idx] = s;
}

// ---------------- softmax over rows of attn [N,N] ----------------
__global__ __launch_bounds__(256) void softmax_rows_k(float* __restrict__ attn) {
    float* row = attn + (long)blockIdx.x * GN;
    const int tid = threadIdx.x;
    float v[8];
    float m = -1e30f;
#pragma unroll
    for (int i = 0; i < 8; ++i) {
        v[i] = row[tid + (i << 8)];
        m = fmaxf(m, v[i]);
    }
    m = block_max(m);
    float s = 0.f;
#pragma unroll
    for (int i = 0; i < 8; ++i) {
        v[i] = __expf(v[i] - m);
        s += v[i];
    }
    s = block_sum(s);
    float inv = 1.f / s;
#pragma unroll
    for (int i = 0; i < 8; ++i) row[tid + (i << 8)] = v[i] * inv;
}

// ---------------- column sums over q ----------------
__global__ __launch_bounds__(256) void colsum_k(const float* __restrict__ attn,
                                                float* __restrict__ cs) {
    int k = blockIdx.x * 256 + threadIdx.x;
    float s = 0.f;
    for (int q = 0; q < GN; ++q) s += attn[(long)q * GN + k];
    cs[k] = s;
}

// ---------------- attn[q,k] /= (1e-9 + cs[k]) ----------------
__global__ __launch_bounds__(256) void attn_scale_k(float* __restrict__ attn,
                                                    const float* __restrict__ cs) {
    long idx = ((long)blockIdx.x * 256 + threadIdx.x) * 4;
    int k = (int)(idx & (GN - 1));
    float4 v = *(float4*)(attn + idx);
    v.x /= (1e-9f + cs[k + 0]);
    v.y /= (1e-9f + cs[k + 1]);
    v.z /= (1e-9f + cs[k + 2]);
    v.w /= (1e-9f + cs[k + 3]);
    *(float4*)(attn + idx) = v;
}

// ---------------- BN stats: fold into scale/shift per channel ----------------
__global__ __launch_bounds__(256) void bn_stats_k(const float* __restrict__ d,
                                                  const float* __restrict__ gamma,
                                                  const float* __restrict__ beta,
                                                  float* __restrict__ sc,
                                                  float* __restrict__ sh) {
    int c = blockIdx.x;  // 0..511
    float s = 0.f, s2 = 0.f;
    for (int b = 0; b < GB; ++b) {
        const float* p = d + ((long)b * 512 + c) * GN;
        for (int n = threadIdx.x; n < GN; n += 256) {
            float v = p[n];
            s += v;
            s2 = fmaf(v, v, s2);
        }
    }
    s = block_sum(s);
    s2 = block_sum(s2);
    if (threadIdx.x == 0) {
        const float cnt = (float)(GB * GN);
        float mu = s / cnt;
        float var = s2 / cnt - mu * mu;
        float r = rsqrtf(var + 1e-5f);
        float gm = gamma[c] * r;
        sc[c] = gm;
        sh[c] = beta[c] - gm * mu;
    }
}

// ---------------- h3 += relu(d*sc[c]+sh[c]) in place ----------------
__global__ __launch_bounds__(256) void bn_apply_k(float* __restrict__ h3,
                                                  const float* __restrict__ d,
                                                  const float* __restrict__ sc,
                                                  const float* __restrict__ sh) {
    long idx = ((long)blockIdx.x * 256 + threadIdx.x) * 4;
    int c = (int)((idx >> 11) & 511);
    float a = sc[c], b = sh[c];
    float4 dv = *(const float4*)(d + idx);
    float4 hv = *(const float4*)(h3 + idx);
    hv.x += fmaxf(fmaf(dv.x, a, b), 0.f);
    hv.y += fmaxf(fmaf(dv.y, a, b), 0.f);
    hv.z += fmaxf(fmaf(dv.z, a, b), 0.f);
    hv.w += fmaxf(fmaf(dv.w, a, b), 0.f);
    *(float4*)(h3 + idx) = hv;
}

extern "C" void kernel_launch(void* const* d_in, const int* in_sizes, int n_in,
                              void* d_out, int out_size, void* d_ws, size_t ws_size,
                              hipStream_t stream) {
    const float* x = (const float*)d_in[0];
    const float* w1 = (const float*)d_in[1];
    const float* b1 = (const float*)d_in[2];
    const float* w2 = (const float*)d_in[3];
    const float* b2 = (const float*)d_in[4];
    const float* w3 = (const float*)d_in[5];
    const float* b3 = (const float*)d_in[6];
    const float* w4 = (const float*)d_in[7];
    const float* b4 = (const float*)d_in[8];
    const float* wqk = (const float*)d_in[9];
    const float* wv = (const float*)d_in[10];
    const float* bv = (const float*)d_in[11];
    const float* wt = (const float*)d_in[12];
    const float* bt = (const float*)d_in[13];
    const float* gamma = (const float*)d_in[14];
    const float* beta = (const float*)d_in[15];
    float* out = (float*)d_out;

    // workspace carve (floats) — peak ~163 MB
    float* ws = (float*)d_ws;
    float* h3 = ws;                        // [16,512,2048]  16,777,216
    float* dbuf = h3 + 16777216;           // [16,512,2048]  16,777,216
    float* h1 = dbuf;                      //   alias: [16,128,2048] (dead before dbuf written)
    float* h2 = dbuf + 4194304;            //   alias: [16,256,2048] (dead before dbuf written)
    float* attn = dbuf + 16777216;         // [2048,2048]     4,194,304
    float* kb = attn + 4194304;            // [128,2048]        262,144  (per-batch)
    float* xvb = kb + 262144;              // [512,2048]      1,048,576  (per-batch)
    float* xrb = xvb + 1048576;            // [512,2048]      1,048,576  (per-batch)
    float* partial = xrb + 1048576;        // [16,1024,32]      524,288
    float* gbuf = partial + 524288;        // [16,256]
    float* cvec = gbuf + 4096;             // [16,512]
    float* csum = cvec + 8192;             // [2048]
    float* bnsc = csum + 2048;             // [512]
    float* bnsh = bnsc + 512;              // [512]

    // 1. posenc + conv1 + relu -> h1
    posenc_conv1_k<<<GB * GN / 256, 256, 0, stream>>>(x, w1, b1, h1);

    // 2. h2 = w2 @ h1 + b2
    gemm_k<false, false, false, false><<<dim3(32, 4, GB), 256, 0, stream>>>(
        w2, 128, 0, h1, GN, 128LL * GN, nullptr, b2, 0, h2, GN, 256LL * GN,
        256, GN, 128);

    // 3. g = max_n h2
    maxn_k<<<GB * 256, 256, 0, stream>>>(h2, gbuf);

    // 4. cvec = w3[:,256:] @ g + b3
    cvec_k<<<GB * 512 / 256, 256, 0, stream>>>(w3, b3, gbuf, cvec);

    // 5. h3 = relu(w3[:,:256] @ h2 + cvec)
    gemm_k<false, false, true, false><<<dim3(32, 8, GB), 256, 0, stream>>>(
        w3, 512, 0, h2, GN, 256LL * GN, nullptr, cvec, 512, h3, GN, 512LL * GN,
        512, GN, 256);

    // 6. per-batch attention pipeline (small scratch, stream-ordered)
    for (int b = 0; b < GB; ++b) {
        const float* h3b = h3 + (long long)b * 512 * GN;
        // kb = wqk @ h3b            [128,2048]
        gemm_k<false, false, false, false><<<dim3(32, 2, 1), 256, 0, stream>>>(
            wqk, 512, 0, h3b, GN, 0, nullptr, nullptr, 0, kb, GN, 0,
            128, GN, 512);
        // xvb = wv @ h3b + bv       [512,2048]
        gemm_k<false, false, false, false><<<dim3(32, 8, 1), 256, 0, stream>>>(
            wv, 512, 0, h3b, GN, 0, nullptr, bv, 0, xvb, GN, 0,
            512, GN, 512);
        // energy = K^T K            [2048,2048]
        gemm_k<true, false, false, false><<<dim3(32, 32, 1), 256, 0, stream>>>(
            kb, GN, 0, kb, GN, 0, nullptr, nullptr, 0, attn, GN, 0,
            GN, GN, 128);
        softmax_rows_k<<<GN, 256, 0, stream>>>(attn);
        colsum_k<<<GN / 256, 256, 0, stream>>>(attn, csum);
        attn_scale_k<<<GN * GN / 1024, 256, 0, stream>>>(attn, csum);
        // xrb = xvb @ attn^T        [512,2048]
        gemm_k<false, true, false, false><<<dim3(32, 8, 1), 256, 0, stream>>>(
            xvb, GN, 0, attn, GN, 0, nullptr, nullptr, 0, xrb, GN, 0,
            512, GN, GN);
        // dbuf_b = wt @ (h3b - xrb) + bt
        gemm_k<false, false, false, true><<<dim3(32, 8, 1), 256, 0, stream>>>(
            wt, 512, 0, h3b, GN, 0, xrb, bt, 0,
            dbuf + (long long)b * 512 * GN, GN, 0, 512, GN, 512);
    }

    // 7. BN stats -> scale/shift
    bn_stats_k<<<512, 256, 0, stream>>>(dbuf, gamma, beta, bnsc, bnsh);

    // 8. h3 += relu(bn(d)) in place
    bn_apply_k<<<GB * 512 * GN / 1024, 256, 0, stream>>>(h3, dbuf, bnsc, bnsh);

    // 9. fused: partial tile-maxes of w4 @ h3 + b4
    gemm_max_k<<<dim3(32, 16, GB), 256, 0, stream>>>(
        w4, 512, h3, GN, 512LL * GN, b4, partial, 1024, 512);

    // 10. out = max over tiles
    max_final_k<<<GB * 1024 / 256, 256, 0, stream>>>(partial, out);
}

// Round 3
// 803.163 us; speedup vs baseline: 9.0738x; 9.0738x over previous
//
#include <hip/hip_runtime.h>
#include <cmath>

#define GN 2048
#define GB 16

typedef __attribute__((ext_vector_type(8))) short bf8_t;
typedef __attribute__((ext_vector_type(4))) float f4_t;

__device__ __forceinline__ short f2bf(float f) {
    union { float f; unsigned u; } v; v.f = f;
    unsigned r = v.u + 0x7FFFu + ((v.u >> 16) & 1u);
    return (short)(r >> 16);
}
__device__ __forceinline__ float bf2f(short s) {
    union { unsigned u; float f; } v; v.u = ((unsigned)(unsigned short)s) << 16;
    return v.f;
}

// ---------------- reductions ----------------
__device__ __forceinline__ float wave_max(float v) {
#pragma unroll
    for (int o = 32; o > 0; o >>= 1) v = fmaxf(v, __shfl_xor(v, o, 64));
    return v;
}
__device__ __forceinline__ float wave_sum(float v) {
#pragma unroll
    for (int o = 32; o > 0; o >>= 1) v += __shfl_xor(v, o, 64);
    return v;
}
__device__ __forceinline__ float block_max(float v) {
    __shared__ float sm[4];
    v = wave_max(v);
    if ((threadIdx.x & 63) == 0) sm[threadIdx.x >> 6] = v;
    __syncthreads();
    v = fmaxf(fmaxf(sm[0], sm[1]), fmaxf(sm[2], sm[3]));
    __syncthreads();
    return v;
}
__device__ __forceinline__ float block_sum(float v) {
    __shared__ float sm[4];
    v = wave_sum(v);
    if ((threadIdx.x & 63) == 0) sm[threadIdx.x >> 6] = v;
    __syncthreads();
    v = sm[0] + sm[1] + sm[2] + sm[3];
    __syncthreads();
    return v;
}

// ---------------- fp32 -> bf16 convert ----------------
__global__ __launch_bounds__(256) void f2b_k(const float* __restrict__ s,
                                             short* __restrict__ d, int n) {
    int i = blockIdx.x * 256 + threadIdx.x;
    if (i < n) d[i] = f2bf(s[i]);
}

// ---------------- posenc + conv1 + relu -> h1T [32768, 128] bf16 ----------------
__global__ __launch_bounds__(256) void posenc_conv1_k(
    const float* __restrict__ x, const float* __restrict__ w1,
    const float* __restrict__ b1, short* __restrict__ h1) {
    __shared__ float w[128 * 21];
    __shared__ float bb[128];
    __shared__ float se[256][21];
    const int tid = threadIdx.x;
    for (int i = tid; i < 128 * 21; i += 256) w[i] = w1[i];
    if (tid < 128) bb[tid] = b1[tid];
    int p0 = blockIdx.x * 256;
    int p = p0 + tid, b = p >> 11, n = p & (GN - 1);
    const float* xb = x + (long)b * 3 * GN + n;
    float t0 = xb[0], t1 = xb[GN], t2 = xb[2 * GN];
    se[tid][0] = t0; se[tid][1] = t1; se[tid][2] = t2;
    se[tid][3] = sinf(t0); se[tid][4] = sinf(t1); se[tid][5] = sinf(t2);
    se[tid][6] = cosf(t0); se[tid][7] = cosf(t1); se[tid][8] = cosf(t2);
    se[tid][9] = sinf(2.f * t0); se[tid][10] = sinf(2.f * t1); se[tid][11] = sinf(2.f * t2);
    se[tid][12] = cosf(2.f * t0); se[tid][13] = cosf(2.f * t1); se[tid][14] = cosf(2.f * t2);
    se[tid][15] = sinf(4.f * t0); se[tid][16] = sinf(4.f * t1); se[tid][17] = sinf(4.f * t2);
    se[tid][18] = cosf(4.f * t0); se[tid][19] = cosf(4.f * t1); se[tid][20] = cosf(4.f * t2);
    __syncthreads();
    short* outb = h1 + (long)p0 * 128;
    for (int it = 0; it < 128; ++it) {
        int L = it * 256 + tid;
        int pl = L >> 7, o = L & 127;
        float s = bb[o];
        const float* er = se[pl];
        const float* wr = &w[o * 21];
#pragma unroll
        for (int c = 0; c < 21; ++c) s = fmaf(wr[c], er[c], s);
        outb[L] = f2bf(fmaxf(s, 0.f));
    }
}

// ---------------- MFMA GEMM: D[row,col] = sum_k A[row,k]*B[col,k] ----------------
// A bf16 [M,K] lda, B bf16 [N,K] ldb; 128x128 tile, BK=32, 4 waves (2x2 of 64x64).
// MODE: 1=f32 out, 2=bf16 out, 3=both, 4=Cb=bf16(aux - D), 5=col-max partials.
// BIAS: 0 none, 1 per-col, 2 per-row, 3 per-col with batch row-block (stride).
template <int MODE, int BIAS, bool RELU>
__global__ __launch_bounds__(256) void mm_k(
    const short* __restrict__ A, int lda, long long aB,
    const short* __restrict__ B, int ldb, long long bB,
    const float* __restrict__ bias, int biasStride,
    const float* __restrict__ aux, long long auxB,
    float* __restrict__ Cf, long long cfB,
    short* __restrict__ Cb, long long cbB,
    float* __restrict__ Pmax,
    int ldc, int K) {
    const int z = blockIdx.z;
    A += (long long)z * aB;
    B += (long long)z * bB;
    if (MODE == 4) aux += (long long)z * auxB;
    if (MODE & 1) Cf += (long long)z * cfB;
    if (MODE == 2 || MODE == 3 || MODE == 4) Cb += (long long)z * cbB;
    const int row0 = blockIdx.y * 128, col0 = blockIdx.x * 128;
    const int tid = threadIdx.x;
    const int lane = tid & 63, w = tid >> 6;
    const int r = lane & 15, q = lane >> 4;
    const int wr = w >> 1, wc = w & 1;

    __shared__ short lA[4096];  // [128 rows][32 k]
    __shared__ short lB[4096];

    f4_t acc[4][4] = {};

    const int c1 = tid, c2 = tid + 256;
    const int ar1 = c1 >> 2, ak1 = (c1 & 3) * 8;
    const int ar2 = c2 >> 2, ak2 = (c2 & 3) * 8;
    // k-invariant LDS read offsets
    int aoff[4], boff[4];
#pragma unroll
    for (int i = 0; i < 4; ++i) {
        aoff[i] = (wr * 64 + i * 16 + r) * 32 + q * 8;
        boff[i] = (wc * 64 + i * 16 + r) * 32 + q * 8;
    }

    for (int k0 = 0; k0 < K; k0 += 32) {
        __syncthreads();
        *(uint4*)&lA[c1 * 8] = *(const uint4*)(A + (long)(row0 + ar1) * lda + k0 + ak1);
        *(uint4*)&lA[c2 * 8] = *(const uint4*)(A + (long)(row0 + ar2) * lda + k0 + ak2);
        *(uint4*)&lB[c1 * 8] = *(const uint4*)(B + (long)(col0 + ar1) * ldb + k0 + ak1);
        *(uint4*)&lB[c2 * 8] = *(const uint4*)(B + (long)(col0 + ar2) * ldb + k0 + ak2);
        __syncthreads();
        bf8_t av[4], bv[4];
#pragma unroll
        for (int i = 0; i < 4; ++i) av[i] = *(const bf8_t*)(lA + aoff[i]);
#pragma unroll
        for (int j = 0; j < 4; ++j) bv[j] = *(const bf8_t*)(lB + boff[j]);
#pragma unroll
        for (int i = 0; i < 4; ++i)
#pragma unroll
            for (int j = 0; j < 4; ++j)
                acc[i][j] = __builtin_amdgcn_mfma_f32_16x16x32_bf16(av[i], bv[j], acc[i][j], 0, 0, 0);
    }

    if constexpr (MODE == 5) {
        __shared__ float smax[2][128];
#pragma unroll
        for (int j = 0; j < 4; ++j) {
            float vm = -1e30f;
#pragma unroll
            for (int i = 0; i < 4; ++i)
#pragma unroll
                for (int e = 0; e < 4; ++e) vm = fmaxf(vm, acc[i][j][e]);
            vm = fmaxf(vm, __shfl_xor(vm, 16, 64));
            vm = fmaxf(vm, __shfl_xor(vm, 32, 64));
            if (q == 0) smax[wr][wc * 64 + j * 16 + r] = vm;
        }
        __syncthreads();
        if (tid < 128) {
            int gcol = col0 + tid;
            float m = fmaxf(smax[0][tid], smax[1][tid]) + bias[gcol];
            int b = row0 >> 11;
            int nblk = blockIdx.y & 15;
            Pmax[(((long)b * 1024 + gcol) << 4) + nblk] = m;
        }
    } else {
        const int b2d = (BIAS == 3) ? (row0 >> 11) : 0;
#pragma unroll
        for (int j = 0; j < 4; ++j) {
            int gcol = col0 + wc * 64 + j * 16 + r;
            float bvv = 0.f;
            if constexpr (BIAS == 1) bvv = bias[gcol];
            if constexpr (BIAS == 3) bvv = bias[b2d * biasStride + gcol];
#pragma unroll
            for (int i = 0; i < 4; ++i) {
#pragma unroll
                for (int e = 0; e < 4; ++e) {
                    int grow = row0 + wr * 64 + i * 16 + q * 4 + e;
                    float v = acc[i][j][e] + bvv;
                    if constexpr (BIAS == 2) v += bias[grow];
                    if constexpr (RELU) v = fmaxf(v, 0.f);
                    long off = (long)grow * ldc + gcol;
                    if constexpr (MODE == 4) {
                        Cb[off] = f2bf(aux[off] - v);
                    } else {
                        if constexpr (MODE & 1) Cf[off] = v;
                        if constexpr (MODE & 2) Cb[off] = f2bf(v);
                    }
                }
            }
        }
    }
}

// ---------------- maxn over h2T bf16: two-stage ----------------
__global__ __launch_bounds__(256) void maxn1_k(const short* __restrict__ h2,
                                               float* __restrict__ gp) {
    int b = blockIdx.x, s = blockIdx.y, c = threadIdx.x;
    const short* p = h2 + ((long)b * GN + s * 128) * 256 + c;
    float m = -1e30f;
    for (int n = 0; n < 128; ++n) m = fmaxf(m, bf2f(p[(long)n * 256]));
    gp[((b * 16 + s) << 8) + c] = m;
}
__global__ __launch_bounds__(256) void maxn2_k(const float* __restrict__ gp,
                                               float* __restrict__ g) {
    int b = blockIdx.x, c = threadIdx.x;
    float m = -1e30f;
    for (int s = 0; s < 16; ++s) m = fmaxf(m, gp[((b * 16 + s) << 8) + c]);
    g[(b << 8) + c] = m;
}

// ---------------- cvec[b,o] = b3[o] + sum_c w3[o,256+c]*g[b,c] (fp32) ----------------
__global__ __launch_bounds__(256) void cvec_k(const float* __restrict__ w3,
                                              const float* __restrict__ b3,
                                              const float* __restrict__ g,
                                              float* __restrict__ cvec) {
    int idx = blockIdx.x * 256 + threadIdx.x;
    int b = idx >> 9, o = idx & 511;
    const float* gb = g + (b << 8);
    const float* wr = w3 + (long)o * 512 + 256;
    float s = b3[o];
    for (int c = 0; c < 256; ++c) s = fmaf(wr[c], gb[c], s);
    cvec[idx] = s;
}

// ---------------- softmax rows: E fp32 -> Abf bf16 ----------------
__global__ __launch_bounds__(256) void softmax_k(const float* __restrict__ E,
                                                 short* __restrict__ Ab) {
    long base = (long)blockIdx.y * GN * GN + (long)blockIdx.x * GN;
    const float* row = E + base;
    short* ob = Ab + base;
    const int tid = threadIdx.x;
    float v[8];
    float m = -1e30f;
#pragma unroll
    for (int i = 0; i < 8; ++i) {
        v[i] = row[tid + (i << 8)];
        m = fmaxf(m, v[i]);
    }
    m = block_max(m);
    float s = 0.f;
#pragma unroll
    for (int i = 0; i < 8; ++i) {
        v[i] = __expf(v[i] - m);
        s += v[i];
    }
    s = block_sum(s);
    float inv = 1.f / s;
#pragma unroll
    for (int i = 0; i < 8; ++i) ob[tid + (i << 8)] = f2bf(v[i] * inv);
}

// ---------------- column sums over q (two-stage) ----------------
__global__ __launch_bounds__(256) void colsum1_k(const short* __restrict__ Ab,
                                                 float* __restrict__ cp) {
    int kb = blockIdx.x, qs = blockIdx.y, z = blockIdx.z;
    int k = kb * 256 + threadIdx.x;
    const short* p = Ab + (long)z * GN * GN + (long)qs * 64 * GN + k;
    float s = 0.f;
    for (int qq = 0; qq < 64; ++qq) s += bf2f(p[(long)qq * GN]);
    cp[((z * 32 + qs) * GN) + k] = s;
}
__global__ __launch_bounds__(256) void colsum2_k(const float* __restrict__ cp,
                                                 float* __restrict__ cs) {
    int k = blockIdx.x * 256 + threadIdx.x, z = blockIdx.y;
    float s = 1e-9f;
    for (int qs = 0; qs < 32; ++qs) s += cp[((z * 32 + qs) * GN) + k];
    cs[z * GN + k] = s;
}

// ---------------- Abf[q,k] /= cs[k]  (in place, bf16) ----------------
__global__ __launch_bounds__(256) void scale_k(short* __restrict__ Ab,
                                               const float* __restrict__ cs) {
    long idx = ((long)blockIdx.x * 256 + threadIdx.x) * 8;
    int z = (int)(idx >> 22);
    int k = (int)(idx & (GN - 1));
    const float* c = cs + z * GN + k;
    short* p = Ab + idx;
    uint4 u = *(const uint4*)p;
    short* sp = (short*)&u;
#pragma unroll
    for (int e = 0; e < 8; ++e) sp[e] = f2bf(bf2f(sp[e]) / c[e]);
    *(uint4*)p = u;
}

// ---------------- BN stats two-stage on dT fp32 [32768,512] ----------------
__global__ __launch_bounds__(256) void bn1_k(const float* __restrict__ d,
                                             float* __restrict__ bs1,
                                             float* __restrict__ bs2) {
    int s = blockIdx.x, t = threadIdx.x;
    const float* p = d + (long)s * 256 * 512;
    float s0 = 0.f, q0 = 0.f, s1 = 0.f, q1 = 0.f;
    for (int rr = 0; rr < 256; ++rr) {
        float v0 = p[(long)rr * 512 + t];
        float v1 = p[(long)rr * 512 + t + 256];
        s0 += v0; q0 = fmaf(v0, v0, q0);
        s1 += v1; q1 = fmaf(v1, v1, q1);
    }
    bs1[s * 512 + t] = s0; bs1[s * 512 + t + 256] = s1;
    bs2[s * 512 + t] = q0; bs2[s * 512 + t + 256] = q1;
}
__global__ __launch_bounds__(256) void bn2_k(const float* __restrict__ bs1,
                                             const float* __restrict__ bs2,
                                             const float* __restrict__ gamma,
                                             const float* __restrict__ beta,
                                             float* __restrict__ sc,
                                             float* __restrict__ sh) {
    int c = blockIdx.x * 256 + threadIdx.x;
    float s = 0.f, s2 = 0.f;
    for (int i = 0; i < 128; ++i) {
        s += bs1[i * 512 + c];
        s2 += bs2[i * 512 + c];
    }
    const float cnt = (float)(GB * GN);
    float mu = s / cnt;
    float var = s2 / cnt - mu * mu;
    float r = rsqrtf(var + 1e-5f);
    float gm = gamma[c] * r;
    sc[c] = gm;
    sh[c] = beta[c] - gm * mu;
}

// ---------------- h4T = bf16(h3f + relu(d*sc+sh)) ----------------
__global__ __launch_bounds__(256) void bn_apply_k(const float* __restrict__ h3f,
                                                  const float* __restrict__ d,
                                                  const float* __restrict__ sc,
                                                  const float* __restrict__ sh,
                                                  short* __restrict__ h4) {
    long bidx = ((long)blockIdx.x * 256 + threadIdx.x) * 4;
    int c = (int)(bidx & 511);
    float4 d4 = *(const float4*)(d + bidx);
    float4 h4v = *(const float4*)(h3f + bidx);
    float4 a4 = *(const float4*)(sc + c);
    float4 b4 = *(const float4*)(sh + c);
    float r0 = h4v.x + fmaxf(fmaf(d4.x, a4.x, b4.x), 0.f);
    float r1 = h4v.y + fmaxf(fmaf(d4.y, a4.y, b4.y), 0.f);
    float r2 = h4v.z + fmaxf(fmaf(d4.z, a4.z, b4.z), 0.f);
    float r3 = h4v.w + fmaxf(fmaf(d4.w, a4.w, b4.w), 0.f);
    uint2 o;
    o.x = (unsigned short)f2bf(r0) | ((unsigned)(unsigned short)f2bf(r1) << 16);
    o.y = (unsigned short)f2bf(r2) | ((unsigned)(unsigned short)f2bf(r3) << 16);
    *(uint2*)(h4 + bidx) = o;
}

// ---------------- out[i] = max over 16 partials ----------------
__global__ __launch_bounds__(256) void max_final_k(const float* __restrict__ P,
                                                   float* __restrict__ out) {
    int i = blockIdx.x * 256 + threadIdx.x;
    const float* p = P + ((long)i << 4);
    float m = p[0];
#pragma unroll
    for (int j = 1; j < 16; ++j) m = fmaxf(m, p[j]);
    out[i] = m;
}

extern "C" void kernel_launch(void* const* d_in, const int* in_sizes, int n_in,
                              void* d_out, int out_size, void* d_ws, size_t ws_size,
                              hipStream_t stream) {
    const float* x = (const float*)d_in[0];
    const float* w1 = (const float*)d_in[1];
    const float* b1 = (const float*)d_in[2];
    const float* w2 = (const float*)d_in[3];
    const float* b2 = (const float*)d_in[4];
    const float* w3 = (const float*)d_in[5];
    const float* b3 = (const float*)d_in[6];
    const float* w4 = (const float*)d_in[7];
    const float* b4 = (const float*)d_in[8];
    const float* wqk = (const float*)d_in[9];
    const float* wv = (const float*)d_in[10];
    const float* bv = (const float*)d_in[11];
    const float* wt = (const float*)d_in[12];
    const float* bt = (const float*)d_in[13];
    const float* gamma = (const float*)d_in[14];
    const float* beta = (const float*)d_in[15];
    float* out = (float*)d_out;

    // ---- workspace carve (bytes), peak 249,057,280 B (~237.5 MiB) ----
    char* base = (char*)d_ws;
    float* h3f = (float*)base;                    // [32768,512] f32  64 MB
    short* h3b = (short*)(base + 67108864);       // [32768,512] bf16 32 MB
    short* hsT = h3b;                             // alias (h3b dead after xv GEMM)
    short* kT = (short*)(base + 100663296);       // [32768,128] bf16  8 MB
    short* xvc = (short*)(base + 109051904);      // [512,32768] bf16 32 MB (channel-major)
    char* R1 = base + 142606336;                  // 64 MB region
    short* h1T = (short*)R1;                      //   [32768,128] bf16 (early)
    short* h2T = (short*)(R1 + 8388608);          //   [32768,256] bf16 (early)
    float* E = (float*)R1;                        //   [4,2048,2048] f32 (attn groups)
    float* dT = (float*)R1;                       //   [32768,512] f32 (late)
    char* R2 = base + 209715200;                  // 32 MB region
    short* Abf = (short*)R2;                      //   [4,2048,2048] bf16 (attn groups)
    short* h4T = (short*)R2;                      //   [32768,512] bf16 (late)
    char* S = base + 243269632;
    float* gp = (float*)S;                        // 262144
    float* g = (float*)(S + 262144);              // 16384
    float* cvec = (float*)(S + 278528);           // 32768
    float* cp = (float*)(S + 311296);             // 1048576
    float* cs = (float*)(S + 1359872);            // 32768
    float* bs1 = (float*)(S + 1392640);           // 262144
    float* bs2 = (float*)(S + 1654784);           // 262144
    float* bnsc = (float*)(S + 1916928);          // 2048
    float* bnsh = (float*)(S + 1918976);          // 2048
    float* Pmax = (float*)(S + 1921024);          // 1048576
    short* w2b = (short*)(S + 2969600);
    short* w3b = (short*)(S + 3035136);
    short* wqkb = (short*)(S + 3559424);
    short* wvb = (short*)(S + 3690496);
    short* wtb = (short*)(S + 4214784);
    short* w4b = (short*)(S + 4739072);

    // 0. weight converts to bf16
    f2b_k<<<128, 256, 0, stream>>>(w2, w2b, 256 * 128);
    f2b_k<<<1024, 256, 0, stream>>>(w3, w3b, 512 * 512);
    f2b_k<<<256, 256, 0, stream>>>(wqk, wqkb, 128 * 512);
    f2b_k<<<1024, 256, 0, stream>>>(wv, wvb, 512 * 512);
    f2b_k<<<1024, 256, 0, stream>>>(wt, wtb, 512 * 512);
    f2b_k<<<2048, 256, 0, stream>>>(w4, w4b, 1024 * 512);

    // 1. posenc + conv1 + relu -> h1T
    posenc_conv1_k<<<128, 256, 0, stream>>>(x, w1, b1, h1T);

    // 2. h2T = h1T @ w2^T + b2  (no relu)
    mm_k<2, 1, false><<<dim3(2, 256, 1), 256, 0, stream>>>(
        h1T, 128, 0, w2b, 128, 0, b2, 0, nullptr, 0,
        nullptr, 0, h2T, 0, nullptr, 256, 128);

    // 3. g[b,c] = max_n h2T
    maxn1_k<<<dim3(GB, 16), 256, 0, stream>>>(h2T, gp);
    maxn2_k<<<GB, 256, 0, stream>>>(gp, g);

    // 4. cvec = w3[:,256:] @ g + b3 (fp32)
    cvec_k<<<32, 256, 0, stream>>>(w3, b3, g, cvec);

    // 5. h3 = relu(h2T @ w3[:,:256]^T + cvec)  -> fp32 + bf16
    mm_k<3, 3, true><<<dim3(4, 256, 1), 256, 0, stream>>>(
        h2T, 256, 0, w3b, 512, 0, cvec, 512, nullptr, 0,
        h3f, 0, h3b, 0, nullptr, 512, 256);

    // 6. kT = h3b @ wqk^T
    mm_k<2, 0, false><<<dim3(1, 256, 1), 256, 0, stream>>>(
        h3b, 512, 0, wqkb, 512, 0, nullptr, 0, nullptr, 0,
        nullptr, 0, kT, 0, nullptr, 128, 512);

    // 7. xv channel-major: D[c, point] = wv @ h3 + bv(row)
    mm_k<2, 2, false><<<dim3(256, 4, 1), 256, 0, stream>>>(
        wvb, 512, 0, h3b, 512, 0, bv, 0, nullptr, 0,
        nullptr, 0, xvc, 0, nullptr, 32768, 512);

    // 8. attention in groups of 4 batches
    for (int gix = 0; gix < 4; ++gix) {
        const short* kg = kT + (long)gix * 4 * GN * 128;
        // energy = kT kT^T (per batch in group)
        mm_k<1, 0, false><<<dim3(16, 16, 4), 256, 0, stream>>>(
            kg, 128, (long long)GN * 128, kg, 128, (long long)GN * 128,
            nullptr, 0, nullptr, 0, E, (long long)GN * GN, nullptr, 0,
            nullptr, GN, 128);
        softmax_k<<<dim3(GN, 4), 256, 0, stream>>>(E, Abf);
        colsum1_k<<<dim3(8, 32, 4), 256, 0, stream>>>(Abf, cp);
        colsum2_k<<<dim3(8, 4), 256, 0, stream>>>(cp, cs);
        scale_k<<<8192, 256, 0, stream>>>(Abf, cs);
        // xr (fused): hsT = bf16(h3f - attn @ xv^T)
        mm_k<4, 0, false><<<dim3(4, 16, 4), 256, 0, stream>>>(
            Abf, GN, (long long)GN * GN,
            xvc + (long)gix * 4 * GN, 32768, (long long)GN,
            nullptr, 0,
            h3f + (long)gix * 4 * GN * 512, (long long)GN * 512,
            nullptr, 0,
            hsT + (long)gix * 4 * GN * 512, (long long)GN * 512,
            nullptr, 512, GN);
    }

    // 9. dT = hsT @ wt^T + bt (fp32)
    mm_k<1, 1, false><<<dim3(4, 256, 1), 256, 0, stream>>>(
        hsT, 512, 0, wtb, 512, 0, bt, 0, nullptr, 0,
        dT, 0, nullptr, 0, nullptr, 512, 512);

    // 10. BN stats
    bn1_k<<<128, 256, 0, stream>>>(dT, bs1, bs2);
    bn2_k<<<2, 256, 0, stream>>>(bs1, bs2, gamma, beta, bnsc, bnsh);

    // 11. h4T = bf16(h3f + relu(bn(dT)))
    bn_apply_k<<<16384, 256, 0, stream>>>(h3f, dT, bnsc, bnsh, h4T);

    // 12. fused final conv + per-tile col max -> Pmax
    mm_k<5, 1, false><<<dim3(8, 256, 1), 256, 0, stream>>>(
        h4T, 512, 0, w4b, 512, 0, b4, 0, nullptr, 0,
        nullptr, 0, nullptr, 0, Pmax, 1024, 512);

    // 13. out = max over tiles
    max_final_k<<<64, 256, 0, stream>>>(Pmax, out);
}

// Round 4
// 763.734 us; speedup vs baseline: 9.5423x; 1.0516x over previous
//
#include <hip/hip_runtime.h>
#include <cmath>

#define GN 2048
#define GB 16

typedef __attribute__((ext_vector_type(8))) short bf8_t;
typedef __attribute__((ext_vector_type(4))) float f4_t;

__device__ __forceinline__ short f2bf(float f) {
    union { float f; unsigned u; } v; v.f = f;
    unsigned r = v.u + 0x7FFFu + ((v.u >> 16) & 1u);
    return (short)(r >> 16);
}
__device__ __forceinline__ float bf2f(short s) {
    union { unsigned u; float f; } v; v.u = ((unsigned)(unsigned short)s) << 16;
    return v.f;
}

// async 16B/lane global->LDS (wave-uniform LDS base, lane i lands at base+i*16)
__device__ __forceinline__ void load16_lds(const short* g, short* l) {
    __builtin_amdgcn_global_load_lds(
        (const __attribute__((address_space(1))) unsigned int*)g,
        (__attribute__((address_space(3))) unsigned int*)l, 16, 0, 0);
}

// ---------------- reductions ----------------
__device__ __forceinline__ float wave_max(float v) {
#pragma unroll
    for (int o = 32; o > 0; o >>= 1) v = fmaxf(v, __shfl_xor(v, o, 64));
    return v;
}
__device__ __forceinline__ float wave_sum(float v) {
#pragma unroll
    for (int o = 32; o > 0; o >>= 1) v += __shfl_xor(v, o, 64);
    return v;
}
__device__ __forceinline__ float block_max(float v) {
    __shared__ float sm[4];
    v = wave_max(v);
    if ((threadIdx.x & 63) == 0) sm[threadIdx.x >> 6] = v;
    __syncthreads();
    v = fmaxf(fmaxf(sm[0], sm[1]), fmaxf(sm[2], sm[3]));
    __syncthreads();
    return v;
}
__device__ __forceinline__ float block_sum(float v) {
    __shared__ float sm[4];
    v = wave_sum(v);
    if ((threadIdx.x & 63) == 0) sm[threadIdx.x >> 6] = v;
    __syncthreads();
    v = sm[0] + sm[1] + sm[2] + sm[3];
    __syncthreads();
    return v;
}

// ---------------- fp32 -> bf16 convert ----------------
__global__ __launch_bounds__(256) void f2b_k(const float* __restrict__ s,
                                             short* __restrict__ d, int n) {
    int i = blockIdx.x * 256 + threadIdx.x;
    if (i < n) d[i] = f2bf(s[i]);
}

// ---------------- posenc + conv1 + relu -> h1T [32768, 128] bf16 ----------------
__global__ __launch_bounds__(256) void posenc_conv1_k(
    const float* __restrict__ x, const float* __restrict__ w1,
    const float* __restrict__ b1, short* __restrict__ h1) {
    __shared__ float w[128 * 21];
    __shared__ float bb[128];
    __shared__ float se[256][21];
    const int tid = threadIdx.x;
    for (int i = tid; i < 128 * 21; i += 256) w[i] = w1[i];
    if (tid < 128) bb[tid] = b1[tid];
    int p0 = blockIdx.x * 256;
    int p = p0 + tid, b = p >> 11, n = p & (GN - 1);
    const float* xb = x + (long)b * 3 * GN + n;
    float t0 = xb[0], t1 = xb[GN], t2 = xb[2 * GN];
    se[tid][0] = t0; se[tid][1] = t1; se[tid][2] = t2;
    se[tid][3] = sinf(t0); se[tid][4] = sinf(t1); se[tid][5] = sinf(t2);
    se[tid][6] = cosf(t0); se[tid][7] = cosf(t1); se[tid][8] = cosf(t2);
    se[tid][9] = sinf(2.f * t0); se[tid][10] = sinf(2.f * t1); se[tid][11] = sinf(2.f * t2);
    se[tid][12] = cosf(2.f * t0); se[tid][13] = cosf(2.f * t1); se[tid][14] = cosf(2.f * t2);
    se[tid][15] = sinf(4.f * t0); se[tid][16] = sinf(4.f * t1); se[tid][17] = sinf(4.f * t2);
    se[tid][18] = cosf(4.f * t0); se[tid][19] = cosf(4.f * t1); se[tid][20] = cosf(4.f * t2);
    __syncthreads();
    short* outb = h1 + (long)p0 * 128;
    for (int it = 0; it < 128; ++it) {
        int L = it * 256 + tid;
        int pl = L >> 7, o = L & 127;
        float s = bb[o];
        const float* er = se[pl];
        const float* wr = &w[o * 21];
#pragma unroll
        for (int c = 0; c < 21; ++c) s = fmaf(wr[c], er[c], s);
        outb[L] = f2bf(fmaxf(s, 0.f));
    }
}

// ---------------- MFMA GEMM: D[row,col] = sum_k A[row,k]*B[col,k] ----------------
// A bf16 [M,K] lda, B bf16 [N,K] ldb; 128x128 tile, BK=32, 4 waves (2x2 of 64x64).
// Async global_load_lds staging with XOR-swizzled LDS (conflict-free ds_read_b128).
// LDS layout: row*32 shorts; 16B-slot p of row holds k-block p ^ ((row>>1)&3).
// MODE: 1=f32 out, 2=bf16 out, 3=both, 4=Cb=bf16(aux - D), 5=col-max partials.
// BIAS: 0 none, 1 per-col, 2 per-row, 3 per-col with batch row-block (stride).
template <int MODE, int BIAS, bool RELU>
__global__ __launch_bounds__(256) void mm_k(
    const short* __restrict__ A, int lda, long long aB,
    const short* __restrict__ B, int ldb, long long bB,
    const float* __restrict__ bias, int biasStride,
    const float* __restrict__ aux, long long auxB,
    float* __restrict__ Cf, long long cfB,
    short* __restrict__ Cb, long long cbB,
    float* __restrict__ Pmax,
    int ldc, int K) {
    const int z = blockIdx.z;
    A += (long long)z * aB;
    B += (long long)z * bB;
    if (MODE == 4) aux += (long long)z * auxB;
    if (MODE & 1) Cf += (long long)z * cfB;
    if (MODE == 2 || MODE == 3 || MODE == 4) Cb += (long long)z * cbB;
    const int row0 = blockIdx.y * 128, col0 = blockIdx.x * 128;
    const int tid = threadIdx.x;
    const int lane = tid & 63, w = tid >> 6;
    const int r = lane & 15, q = lane >> 4;
    const int wr = w >> 1, wc = w & 1;

    __shared__ short lA[4096];  // [128 rows][32 k] swizzled
    __shared__ short lB[4096];

    f4_t acc[4][4] = {};

    // staging source mapping (per lane): row-in-chunk, swizzled k-block
    const int sRow = lane >> 2;                       // 0..15
    const int sKb = (lane & 3) ^ ((lane >> 3) & 3);   // source k-block for dest slot lane&3
    const long aRow = (long)(row0 + w * 32 + sRow) * lda + sKb * 8;
    const long bRow = (long)(col0 + w * 32 + sRow) * ldb + sKb * 8;
    short* ldsA0 = lA + (w * 32) * 32;
    short* ldsA1 = lA + (w * 32 + 16) * 32;
    short* ldsB0 = lB + (w * 32) * 32;
    short* ldsB1 = lB + (w * 32 + 16) * 32;

    // swizzled k-invariant fragment read offsets (shorts)
    const int sw = (q ^ ((r >> 1) & 3)) * 8;
    int aoff[4], boff[4];
#pragma unroll
    for (int i = 0; i < 4; ++i) {
        aoff[i] = (wr * 64 + i * 16 + r) * 32 + sw;
        boff[i] = (wc * 64 + i * 16 + r) * 32 + sw;
    }

    for (int k0 = 0; k0 < K; k0 += 32) {
        __syncthreads();  // previous tile fully consumed
        load16_lds(A + aRow + k0, ldsA0);
        load16_lds(A + aRow + (long)16 * lda + k0, ldsA1);
        load16_lds(B + bRow + k0, ldsB0);
        load16_lds(B + bRow + (long)16 * ldb + k0, ldsB1);
        __syncthreads();  // drains vmcnt -> LDS tile visible
        bf8_t av[4], bv[4];
#pragma unroll
        for (int i = 0; i < 4; ++i) av[i] = *(const bf8_t*)(lA + aoff[i]);
#pragma unroll
        for (int j = 0; j < 4; ++j) bv[j] = *(const bf8_t*)(lB + boff[j]);
#pragma unroll
        for (int i = 0; i < 4; ++i)
#pragma unroll
            for (int j = 0; j < 4; ++j)
                acc[i][j] = __builtin_amdgcn_mfma_f32_16x16x32_bf16(av[i], bv[j], acc[i][j], 0, 0, 0);
    }

    if constexpr (MODE == 5) {
        __shared__ float smax[2][128];
#pragma unroll
        for (int j = 0; j < 4; ++j) {
            float vm = -1e30f;
#pragma unroll
            for (int i = 0; i < 4; ++i)
#pragma unroll
                for (int e = 0; e < 4; ++e) vm = fmaxf(vm, acc[i][j][e]);
            vm = fmaxf(vm, __shfl_xor(vm, 16, 64));
            vm = fmaxf(vm, __shfl_xor(vm, 32, 64));
            if (q == 0) smax[wr][wc * 64 + j * 16 + r] = vm;
        }
        __syncthreads();
        if (tid < 128) {
            int gcol = col0 + tid;
            float m = fmaxf(smax[0][tid], smax[1][tid]) + bias[gcol];
            int b = row0 >> 11;
            int nblk = blockIdx.y & 15;
            Pmax[(((long)b * 1024 + gcol) << 4) + nblk] = m;
        }
    } else {
        const int b2d = (BIAS == 3) ? (row0 >> 11) : 0;
#pragma unroll
        for (int j = 0; j < 4; ++j) {
            int gcol = col0 + wc * 64 + j * 16 + r;
            float bvv = 0.f;
            if constexpr (BIAS == 1) bvv = bias[gcol];
            if constexpr (BIAS == 3) bvv = bias[b2d * biasStride + gcol];
#pragma unroll
            for (int i = 0; i < 4; ++i) {
#pragma unroll
                for (int e = 0; e < 4; ++e) {
                    int grow = row0 + wr * 64 + i * 16 + q * 4 + e;
                    float v = acc[i][j][e] + bvv;
                    if constexpr (BIAS == 2) v += bias[grow];
                    if constexpr (RELU) v = fmaxf(v, 0.f);
                    long off = (long)grow * ldc + gcol;
                    if constexpr (MODE == 4) {
                        Cb[off] = f2bf(aux[off] - v);
                    } else {
                        if constexpr (MODE & 1) Cf[off] = v;
                        if constexpr (MODE & 2) Cb[off] = f2bf(v);
                    }
                }
            }
        }
    }
}

// ---------------- maxn over h2T bf16: two-stage ----------------
__global__ __launch_bounds__(256) void maxn1_k(const short* __restrict__ h2,
                                               float* __restrict__ gp) {
    int b = blockIdx.x, s = blockIdx.y, c = threadIdx.x;
    const short* p = h2 + ((long)b * GN + s * 128) * 256 + c;
    float m = -1e30f;
    for (int n = 0; n < 128; ++n) m = fmaxf(m, bf2f(p[(long)n * 256]));
    gp[((b * 16 + s) << 8) + c] = m;
}
__global__ __launch_bounds__(256) void maxn2_k(const float* __restrict__ gp,
                                               float* __restrict__ g) {
    int b = blockIdx.x, c = threadIdx.x;
    float m = -1e30f;
    for (int s = 0; s < 16; ++s) m = fmaxf(m, gp[((b * 16 + s) << 8) + c]);
    g[(b << 8) + c] = m;
}

// ---------------- cvec[b,o] = b3[o] + sum_c w3[o,256+c]*g[b,c] (fp32) ----------------
__global__ __launch_bounds__(256) void cvec_k(const float* __restrict__ w3,
                                              const float* __restrict__ b3,
                                              const float* __restrict__ g,
                                              float* __restrict__ cvec) {
    int idx = blockIdx.x * 256 + threadIdx.x;
    int b = idx >> 9, o = idx & 511;
    const float* gb = g + (b << 8);
    const float* wr = w3 + (long)o * 512 + 256;
    float s = b3[o];
    for (int c = 0; c < 256; ++c) s = fmaf(wr[c], gb[c], s);
    cvec[idx] = s;
}

// ---------------- softmax rows: E fp32 -> Abf bf16 ----------------
__global__ __launch_bounds__(256) void softmax_k(const float* __restrict__ E,
                                                 short* __restrict__ Ab) {
    long base = (long)blockIdx.y * GN * GN + (long)blockIdx.x * GN;
    const float* row = E + base;
    short* ob = Ab + base;
    const int tid = threadIdx.x;
    float v[8];
    float m = -1e30f;
#pragma unroll
    for (int i = 0; i < 8; ++i) {
        v[i] = row[tid + (i << 8)];
        m = fmaxf(m, v[i]);
    }
    m = block_max(m);
    float s = 0.f;
#pragma unroll
    for (int i = 0; i < 8; ++i) {
        v[i] = __expf(v[i] - m);
        s += v[i];
    }
    s = block_sum(s);
    float inv = 1.f / s;
#pragma unroll
    for (int i = 0; i < 8; ++i) ob[tid + (i << 8)] = f2bf(v[i] * inv);
}

// ---------------- column sums over q (two-stage) ----------------
__global__ __launch_bounds__(256) void colsum1_k(const short* __restrict__ Ab,
                                                 float* __restrict__ cp) {
    int kb = blockIdx.x, qs = blockIdx.y, z = blockIdx.z;
    int k = kb * 256 + threadIdx.x;
    const short* p = Ab + (long)z * GN * GN + (long)qs * 64 * GN + k;
    float s = 0.f;
    for (int qq = 0; qq < 64; ++qq) s += bf2f(p[(long)qq * GN]);
    cp[((z * 32 + qs) * GN) + k] = s;
}
__global__ __launch_bounds__(256) void colsum2_k(const float* __restrict__ cp,
                                                 float* __restrict__ cs) {
    int k = blockIdx.x * 256 + threadIdx.x, z = blockIdx.y;
    float s = 1e-9f;
    for (int qs = 0; qs < 32; ++qs) s += cp[((z * 32 + qs) * GN) + k];
    cs[z * GN + k] = s;
}

// ---------------- xvc[:, group cols] /= cs  (in place; folds L1 renorm into xv) ----------------
__global__ __launch_bounds__(256) void xvscale_k(short* __restrict__ xvc,
                                                 const float* __restrict__ cs,
                                                 int gix) {
    int idx = (blockIdx.x * 256 + threadIdx.x) * 4;  // over 512*8192
    int c = idx >> 13, j = idx & 8191;
    short* p = xvc + (long)c * 32768 + gix * 8192 + j;
    float4 cv = *(const float4*)(cs + j);
    uint2 u = *(const uint2*)p;
    short* sp = (short*)&u;
    sp[0] = f2bf(bf2f(sp[0]) / cv.x);
    sp[1] = f2bf(bf2f(sp[1]) / cv.y);
    sp[2] = f2bf(bf2f(sp[2]) / cv.z);
    sp[3] = f2bf(bf2f(sp[3]) / cv.w);
    *(uint2*)p = u;
}

// ---------------- BN stats two-stage on dT fp32 [32768,512] ----------------
__global__ __launch_bounds__(256) void bn1_k(const float* __restrict__ d,
                                             float* __restrict__ bs1,
                                             float* __restrict__ bs2) {
    int s = blockIdx.x, t = threadIdx.x;
    const float* p = d + (long)s * 256 * 512;
    float s0 = 0.f, q0 = 0.f, s1 = 0.f, q1 = 0.f;
    for (int rr = 0; rr < 256; ++rr) {
        float v0 = p[(long)rr * 512 + t];
        float v1 = p[(long)rr * 512 + t + 256];
        s0 += v0; q0 = fmaf(v0, v0, q0);
        s1 += v1; q1 = fmaf(v1, v1, q1);
    }
    bs1[s * 512 + t] = s0; bs1[s * 512 + t + 256] = s1;
    bs2[s * 512 + t] = q0; bs2[s * 512 + t + 256] = q1;
}
__global__ __launch_bounds__(256) void bn2_k(const float* __restrict__ bs1,
                                             const float* __restrict__ bs2,
                                             const float* __restrict__ gamma,
                                             const float* __restrict__ beta,
                                             float* __restrict__ sc,
                                             float* __restrict__ sh) {
    int c = blockIdx.x * 256 + threadIdx.x;
    float s = 0.f, s2 = 0.f;
    for (int i = 0; i < 128; ++i) {
        s += bs1[i * 512 + c];
        s2 += bs2[i * 512 + c];
    }
    const float cnt = (float)(GB * GN);
    float mu = s / cnt;
    float var = s2 / cnt - mu * mu;
    float r = rsqrtf(var + 1e-5f);
    float gm = gamma[c] * r;
    sc[c] = gm;
    sh[c] = beta[c] - gm * mu;
}

// ---------------- h4T = bf16(h3f + relu(d*sc+sh)) ----------------
__global__ __launch_bounds__(256) void bn_apply_k(const float* __restrict__ h3f,
                                                  const float* __restrict__ d,
                                                  const float* __restrict__ sc,
                                                  const float* __restrict__ sh,
                                                  short* __restrict__ h4) {
    long bidx = ((long)blockIdx.x * 256 + threadIdx.x) * 4;
    int c = (int)(bidx & 511);
    float4 d4 = *(const float4*)(d + bidx);
    float4 h4v = *(const float4*)(h3f + bidx);
    float4 a4 = *(const float4*)(sc + c);
    float4 b4 = *(const float4*)(sh + c);
    float r0 = h4v.x + fmaxf(fmaf(d4.x, a4.x, b4.x), 0.f);
    float r1 = h4v.y + fmaxf(fmaf(d4.y, a4.y, b4.y), 0.f);
    float r2 = h4v.z + fmaxf(fmaf(d4.z, a4.z, b4.z), 0.f);
    float r3 = h4v.w + fmaxf(fmaf(d4.w, a4.w, b4.w), 0.f);
    uint2 o;
    o.x = (unsigned short)f2bf(r0) | ((unsigned)(unsigned short)f2bf(r1) << 16);
    o.y = (unsigned short)f2bf(r2) | ((unsigned)(unsigned short)f2bf(r3) << 16);
    *(uint2*)(h4 + bidx) = o;
}

// ---------------- out[i] = max over 16 partials ----------------
__global__ __launch_bounds__(256) void max_final_k(const float* __restrict__ P,
                                                   float* __restrict__ out) {
    int i = blockIdx.x * 256 + threadIdx.x;
    const float* p = P + ((long)i << 4);
    float m = p[0];
#pragma unroll
    for (int j = 1; j < 16; ++j) m = fmaxf(m, p[j]);
    out[i] = m;
}

extern "C" void kernel_launch(void* const* d_in, const int* in_sizes, int n_in,
                              void* d_out, int out_size, void* d_ws, size_t ws_size,
                              hipStream_t stream) {
    const float* x = (const float*)d_in[0];
    const float* w1 = (const float*)d_in[1];
    const float* b1 = (const float*)d_in[2];
    const float* w2 = (const float*)d_in[3];
    const float* b2 = (const float*)d_in[4];
    const float* w3 = (const float*)d_in[5];
    const float* b3 = (const float*)d_in[6];
    const float* w4 = (const float*)d_in[7];
    const float* b4 = (const float*)d_in[8];
    const float* wqk = (const float*)d_in[9];
    const float* wv = (const float*)d_in[10];
    const float* bv = (const float*)d_in[11];
    const float* wt = (const float*)d_in[12];
    const float* bt = (const float*)d_in[13];
    const float* gamma = (const float*)d_in[14];
    const float* beta = (const float*)d_in[15];
    float* out = (float*)d_out;

    // ---- workspace carve (bytes), peak ~237.5 MiB (unchanged from r3, known-good) ----
    char* base = (char*)d_ws;
    float* h3f = (float*)base;                    // [32768,512] f32  64 MB
    short* h3b = (short*)(base + 67108864);       // [32768,512] bf16 32 MB
    short* hsT = h3b;                             // alias (h3b dead after xv GEMM)
    short* kT = (short*)(base + 100663296);       // [32768,128] bf16  8 MB
    short* xvc = (short*)(base + 109051904);      // [512,32768] bf16 32 MB (channel-major)
    char* R1 = base + 142606336;                  // 64 MB region
    short* h1T = (short*)R1;                      //   [32768,128] bf16 (early)
    short* h2T = (short*)(R1 + 8388608);          //   [32768,256] bf16 (early)
    float* E = (float*)R1;                        //   [4,2048,2048] f32 (attn groups)
    float* dT = (float*)R1;                       //   [32768,512] f32 (late)
    char* R2 = base + 209715200;                  // 32 MB region
    short* Abf = (short*)R2;                      //   [4,2048,2048] bf16 (attn groups)
    short* h4T = (short*)R2;                      //   [32768,512] bf16 (late)
    char* S = base + 243269632;
    float* gp = (float*)S;                        // 262144
    float* g = (float*)(S + 262144);              // 16384
    float* cvec = (float*)(S + 278528);           // 32768
    float* cp = (float*)(S + 311296);             // 1048576
    float* cs = (float*)(S + 1359872);            // 32768
    float* bs1 = (float*)(S + 1392640);           // 262144
    float* bs2 = (float*)(S + 1654784);           // 262144
    float* bnsc = (float*)(S + 1916928);          // 2048
    float* bnsh = (float*)(S + 1918976);          // 2048
    float* Pmax = (float*)(S + 1921024);          // 1048576
    short* w2b = (short*)(S + 2969600);
    short* w3b = (short*)(S + 3035136);
    short* wqkb = (short*)(S + 3559424);
    short* wvb = (short*)(S + 3690496);
    short* wtb = (short*)(S + 4214784);
    short* w4b = (short*)(S + 4739072);

    // 0. weight converts to bf16
    f2b_k<<<128, 256, 0, stream>>>(w2, w2b, 256 * 128);
    f2b_k<<<1024, 256, 0, stream>>>(w3, w3b, 512 * 512);
    f2b_k<<<256, 256, 0, stream>>>(wqk, wqkb, 128 * 512);
    f2b_k<<<1024, 256, 0, stream>>>(wv, wvb, 512 * 512);
    f2b_k<<<1024, 256, 0, stream>>>(wt, wtb, 512 * 512);
    f2b_k<<<2048, 256, 0, stream>>>(w4, w4b, 1024 * 512);

    // 1. posenc + conv1 + relu -> h1T
    posenc_conv1_k<<<128, 256, 0, stream>>>(x, w1, b1, h1T);

    // 2. h2T = h1T @ w2^T + b2  (no relu)
    mm_k<2, 1, false><<<dim3(2, 256, 1), 256, 0, stream>>>(
        h1T, 128, 0, w2b, 128, 0, b2, 0, nullptr, 0,
        nullptr, 0, h2T, 0, nullptr, 256, 128);

    // 3. g[b,c] = max_n h2T
    maxn1_k<<<dim3(GB, 16), 256, 0, stream>>>(h2T, gp);
    maxn2_k<<<GB, 256, 0, stream>>>(gp, g);

    // 4. cvec = w3[:,256:] @ g + b3 (fp32)
    cvec_k<<<32, 256, 0, stream>>>(w3, b3, g, cvec);

    // 5. h3 = relu(h2T @ w3[:,:256]^T + cvec)  -> fp32 + bf16
    mm_k<3, 3, true><<<dim3(4, 256, 1), 256, 0, stream>>>(
        h2T, 256, 0, w3b, 512, 0, cvec, 512, nullptr, 0,
        h3f, 0, h3b, 0, nullptr, 512, 256);

    // 6. kT = h3b @ wqk^T
    mm_k<2, 0, false><<<dim3(1, 256, 1), 256, 0, stream>>>(
        h3b, 512, 0, wqkb, 512, 0, nullptr, 0, nullptr, 0,
        nullptr, 0, kT, 0, nullptr, 128, 512);

    // 7. xv channel-major: D[c, point] = wv @ h3 + bv(row)
    mm_k<2, 2, false><<<dim3(256, 4, 1), 256, 0, stream>>>(
        wvb, 512, 0, h3b, 512, 0, bv, 0, nullptr, 0,
        nullptr, 0, xvc, 0, nullptr, 32768, 512);

    // 8. attention in groups of 4 batches
    for (int gix = 0; gix < 4; ++gix) {
        const short* kg = kT + (long)gix * 4 * GN * 128;
        // energy = kT kT^T (per batch in group)
        mm_k<1, 0, false><<<dim3(16, 16, 4), 256, 0, stream>>>(
            kg, 128, (long long)GN * 128, kg, 128, (long long)GN * 128,
            nullptr, 0, nullptr, 0, E, (long long)GN * GN, nullptr, 0,
            nullptr, GN, 128);
        softmax_k<<<dim3(GN, 4), 256, 0, stream>>>(E, Abf);
        colsum1_k<<<dim3(8, 32, 4), 256, 0, stream>>>(Abf, cp);
        colsum2_k<<<dim3(8, 4), 256, 0, stream>>>(cp, cs);
        // fold L1 renorm into xv group slice (in place)
        xvscale_k<<<4096, 256, 0, stream>>>(xvc, cs, gix);
        // xr (fused): hsT = bf16(h3f - attn @ xv^T)
        mm_k<4, 0, false><<<dim3(4, 16, 4), 256, 0, stream>>>(
            Abf, GN, (long long)GN * GN,
            xvc + (long)gix * 4 * GN, 32768, (long long)GN,
            nullptr, 0,
            h3f + (long)gix * 4 * GN * 512, (long long)GN * 512,
            nullptr, 0,
            hsT + (long)gix * 4 * GN * 512, (long long)GN * 512,
            nullptr, 512, GN);
    }

    // 9. dT = hsT @ wt^T + bt (fp32)
    mm_k<1, 1, false><<<dim3(4, 256, 1), 256, 0, stream>>>(
        hsT, 512, 0, wtb, 512, 0, bt, 0, nullptr, 0,
        dT, 0, nullptr, 0, nullptr, 512, 512);

    // 10. BN stats
    bn1_k<<<128, 256, 0, stream>>>(dT, bs1, bs2);
    bn2_k<<<2, 256, 0, stream>>>(bs1, bs2, gamma, beta, bnsc, bnsh);

    // 11. h4T = bf16(h3f + relu(bn(dT)))
    bn_apply_k<<<16384, 256, 0, stream>>>(h3f, dT, bnsc, bnsh, h4T);

    // 12. fused final conv + per-tile col max -> Pmax
    mm_k<5, 1, false><<<dim3(8, 256, 1), 256, 0, stream>>>(
        h4T, 512, 0, w4b, 512, 0, b4, 0, nullptr, 0,
        nullptr, 0, nullptr, 0, Pmax, 1024, 512);

    // 13. out = max over tiles
    max_final_k<<<64, 256, 0, stream>>>(Pmax, out);
}

// Round 5
// 674.271 us; speedup vs baseline: 10.8083x; 1.1327x over previous
//
#include <hip/hip_runtime.h>
#include <cmath>

#define GN 2048
#define GB 16

typedef __attribute__((ext_vector_type(8))) short bf8_t;
typedef __attribute__((ext_vector_type(4))) float f4_t;

__device__ __forceinline__ short f2bf(float f) {
    union { float f; unsigned u; } v; v.f = f;
    unsigned r = v.u + 0x7FFFu + ((v.u >> 16) & 1u);
    return (short)(r >> 16);
}
__device__ __forceinline__ float bf2f(short s) {
    union { unsigned u; float f; } v; v.u = ((unsigned)(unsigned short)s) << 16;
    return v.f;
}

// async 16B/lane global->LDS (wave-uniform LDS base, lane i lands at base+i*16)
__device__ __forceinline__ void load16_lds(const short* g, short* l) {
    __builtin_amdgcn_global_load_lds(
        (const __attribute__((address_space(1))) unsigned int*)g,
        (__attribute__((address_space(3))) unsigned int*)l, 16, 0, 0);
}

// ---------------- reductions ----------------
__device__ __forceinline__ float wave_max(float v) {
#pragma unroll
    for (int o = 32; o > 0; o >>= 1) v = fmaxf(v, __shfl_xor(v, o, 64));
    return v;
}
__device__ __forceinline__ float wave_sum(float v) {
#pragma unroll
    for (int o = 32; o > 0; o >>= 1) v += __shfl_xor(v, o, 64);
    return v;
}
__device__ __forceinline__ float block_max(float v) {
    __shared__ float sm[4];
    v = wave_max(v);
    if ((threadIdx.x & 63) == 0) sm[threadIdx.x >> 6] = v;
    __syncthreads();
    v = fmaxf(fmaxf(sm[0], sm[1]), fmaxf(sm[2], sm[3]));
    __syncthreads();
    return v;
}
__device__ __forceinline__ float block_sum(float v) {
    __shared__ float sm[4];
    v = wave_sum(v);
    if ((threadIdx.x & 63) == 0) sm[threadIdx.x >> 6] = v;
    __syncthreads();
    v = sm[0] + sm[1] + sm[2] + sm[3];
    __syncthreads();
    return v;
}

// ---------------- fp32 -> bf16 convert ----------------
__global__ __launch_bounds__(256) void f2b_k(const float* __restrict__ s,
                                             short* __restrict__ d, int n) {
    int i = blockIdx.x * 256 + threadIdx.x;
    if (i < n) d[i] = f2bf(s[i]);
}

// ---------------- posenc + conv1 + relu -> h1T [32768, 128] bf16 ----------------
__global__ __launch_bounds__(256) void posenc_conv1_k(
    const float* __restrict__ x, const float* __restrict__ w1,
    const float* __restrict__ b1, short* __restrict__ h1) {
    __shared__ float w[128 * 21];
    __shared__ float bb[128];
    __shared__ float se[256][21];
    const int tid = threadIdx.x;
    for (int i = tid; i < 128 * 21; i += 256) w[i] = w1[i];
    if (tid < 128) bb[tid] = b1[tid];
    int p0 = blockIdx.x * 256;
    int p = p0 + tid, b = p >> 11, n = p & (GN - 1);
    const float* xb = x + (long)b * 3 * GN + n;
    float t0 = xb[0], t1 = xb[GN], t2 = xb[2 * GN];
    se[tid][0] = t0; se[tid][1] = t1; se[tid][2] = t2;
    se[tid][3] = sinf(t0); se[tid][4] = sinf(t1); se[tid][5] = sinf(t2);
    se[tid][6] = cosf(t0); se[tid][7] = cosf(t1); se[tid][8] = cosf(t2);
    se[tid][9] = sinf(2.f * t0); se[tid][10] = sinf(2.f * t1); se[tid][11] = sinf(2.f * t2);
    se[tid][12] = cosf(2.f * t0); se[tid][13] = cosf(2.f * t1); se[tid][14] = cosf(2.f * t2);
    se[tid][15] = sinf(4.f * t0); se[tid][16] = sinf(4.f * t1); se[tid][17] = sinf(4.f * t2);
    se[tid][18] = cosf(4.f * t0); se[tid][19] = cosf(4.f * t1); se[tid][20] = cosf(4.f * t2);
    __syncthreads();
    short* outb = h1 + (long)p0 * 128;
    for (int it = 0; it < 128; ++it) {
        int L = it * 256 + tid;
        int pl = L >> 7, o = L & 127;
        float s = bb[o];
        const float* er = se[pl];
        const float* wr = &w[o * 21];
#pragma unroll
        for (int c = 0; c < 21; ++c) s = fmaf(wr[c], er[c], s);
        outb[L] = f2bf(fmaxf(s, 0.f));
    }
}

// ---------------- MFMA GEMM: D[row,col] = sum_k A[row,k]*B[col,k] ----------------
// Barrier-free wave-tile version: 4 waves per block, each wave owns a private
// 64x64 tile (wr/wc quadrant of a 128x128 block tile) with PRIVATE double-buffered
// LDS staging via global_load_lds — no __syncthreads in the K-loop, prefetch is
// synchronized per-wave with raw s_waitcnt vmcnt(N).
// Grid: blockIdx.x = row tile (M/128), blockIdx.y = col tile (N/128), z = batch.
// (x/y swapped vs a naive launch so blocks sharing an A row-tile get dispatch ids
//  differing by multiples of 8 -> same XCD -> A re-reads hit that XCD's L2.)
// LDS layout per wave-buf: 64 rows x 32 k (shorts); 16B-slot p of row holds
// k-block p ^ ((row>>1)&3) (XOR swizzle, conflict-free ds_read_b128).
// MODE: 1=f32 out, 2=bf16 out, 3=both, 4=Cb=bf16(aux - D), 5=col-max partials.
// BIAS: 0 none, 1 per-col, 2 per-row, 3 per-col (cvec rows per batch).
template <int MODE, int BIAS, bool RELU>
__global__ __launch_bounds__(256) void mm_k(
    const short* __restrict__ A, int lda, long long aB,
    const short* __restrict__ B, int ldb, long long bB,
    const float* __restrict__ bias, int biasStride,
    const float* __restrict__ aux, long long auxB,
    float* __restrict__ Cf, long long cfB,
    short* __restrict__ Cb, long long cbB,
    float* __restrict__ Pmax,
    int ldc, int K) {
    const int z = blockIdx.z;
    A += (long long)z * aB;
    B += (long long)z * bB;
    if (MODE == 4) aux += (long long)z * auxB;
    if (MODE & 1) Cf += (long long)z * cfB;
    if (MODE == 2 || MODE == 3 || MODE == 4) Cb += (long long)z * cbB;
    const int row0 = blockIdx.x * 128, col0 = blockIdx.y * 128;
    const int tid = threadIdx.x;
    const int lane = tid & 63, w = tid >> 6;
    const int r = lane & 15, q = lane >> 4;
    const int wr = w >> 1, wc = w & 1;

    // 64 KB total: per wave 8192 shorts = [Abuf0|Abuf1|Bbuf0|Bbuf1] x 2048
    __shared__ short lds[32768];
    short* lw = lds + w * 8192;

    f4_t acc[4][4] = {};

    // per-lane global source: row (lane>>2) within 16-row DMA chunk, swizzled k-slot
    const int sKb = (lane & 3) ^ ((lane >> 3) & 3);
    const long aG = (long)(row0 + wr * 64 + (lane >> 2)) * lda + sKb * 8;
    const long bG = (long)(col0 + wc * 64 + (lane >> 2)) * ldb + sKb * 8;

    // swizzled k-invariant fragment read offsets (shorts, within a 2048 buf)
    const int sw = (q ^ ((r >> 1) & 3)) * 8;
    int foff[4];
#pragma unroll
    for (int i = 0; i < 4; ++i) foff[i] = (i * 16 + r) * 32 + sw;

    auto stage = [&](int k0, int buf) {
#pragma unroll
        for (int d = 0; d < 4; ++d)
            load16_lds(A + aG + k0 + (long)d * 16 * lda, lw + buf * 2048 + d * 512);
#pragma unroll
        for (int d = 0; d < 4; ++d)
            load16_lds(B + bG + k0 + (long)d * 16 * ldb, lw + 4096 + buf * 2048 + d * 512);
    };

    stage(0, 0);
    int buf = 0;
    for (int k0 = 0; k0 < K; k0 += 32) {
        if (k0 + 32 < K) {
            stage(k0 + 32, buf ^ 1);
            asm volatile("s_waitcnt vmcnt(8)" ::: "memory");  // current tile's 8 DMAs done
        } else {
            asm volatile("s_waitcnt vmcnt(0)" ::: "memory");
        }
        const short* la = lw + buf * 2048;
        const short* lb = lw + 4096 + buf * 2048;
        bf8_t av[4], bv[4];
#pragma unroll
        for (int i = 0; i < 4; ++i) av[i] = *(const bf8_t*)(la + foff[i]);
#pragma unroll
        for (int j = 0; j < 4; ++j) bv[j] = *(const bf8_t*)(lb + foff[j]);
#pragma unroll
        for (int i = 0; i < 4; ++i)
#pragma unroll
            for (int j = 0; j < 4; ++j)
                acc[i][j] = __builtin_amdgcn_mfma_f32_16x16x32_bf16(av[i], bv[j], acc[i][j], 0, 0, 0);
        buf ^= 1;
    }

    if constexpr (MODE == 5) {
        // per-column max over this wave's 64 rows (pure shuffle, no LDS/barrier)
        int b = row0 >> 11;
        int rw = (((row0 >> 6) & 31) + wr * 1);  // row-wave index within batch... row0>>6 = bx*2
        rw = ((blockIdx.x * 2 + wr) & 31);
#pragma unroll
        for (int j = 0; j < 4; ++j) {
            float vm = -1e30f;
#pragma unroll
            for (int i = 0; i < 4; ++i)
#pragma unroll
                for (int e = 0; e < 4; ++e) vm = fmaxf(vm, acc[i][j][e]);
            vm = fmaxf(vm, __shfl_xor(vm, 16, 64));
            vm = fmaxf(vm, __shfl_xor(vm, 32, 64));
            if (q == 0) {
                int gcol = col0 + wc * 64 + j * 16 + r;
                Pmax[(((long)b * 1024 + gcol) << 5) + rw] = vm + bias[gcol];
            }
        }
    } else {
        const int b2d = (BIAS == 3) ? (row0 >> 11) : 0;
#pragma unroll
        for (int j = 0; j < 4; ++j) {
            int gcol = col0 + wc * 64 + j * 16 + r;
            float bvv = 0.f;
            if constexpr (BIAS == 1) bvv = bias[gcol];
            if constexpr (BIAS == 3) bvv = bias[b2d * biasStride + gcol];
#pragma unroll
            for (int i = 0; i < 4; ++i) {
#pragma unroll
                for (int e = 0; e < 4; ++e) {
                    int grow = row0 + wr * 64 + i * 16 + q * 4 + e;
                    float v = acc[i][j][e] + bvv;
                    if constexpr (BIAS == 2) v += bias[grow];
                    if constexpr (RELU) v = fmaxf(v, 0.f);
                    long off = (long)grow * ldc + gcol;
                    if constexpr (MODE == 4) {
                        Cb[off] = f2bf(aux[off] - v);
                    } else {
                        if constexpr (MODE & 1) Cf[off] = v;
                        if constexpr (MODE & 2) Cb[off] = f2bf(v);
                    }
                }
            }
        }
    }
}

// ---------------- maxn over h2T bf16: two-stage ----------------
__global__ __launch_bounds__(256) void maxn1_k(const short* __restrict__ h2,
                                               float* __restrict__ gp) {
    int b = blockIdx.x, s = blockIdx.y, c = threadIdx.x;
    const short* p = h2 + ((long)b * GN + s * 128) * 256 + c;
    float m = -1e30f;
    for (int n = 0; n < 128; ++n) m = fmaxf(m, bf2f(p[(long)n * 256]));
    gp[((b * 16 + s) << 8) + c] = m;
}
__global__ __launch_bounds__(256) void maxn2_k(const float* __restrict__ gp,
                                               float* __restrict__ g) {
    int b = blockIdx.x, c = threadIdx.x;
    float m = -1e30f;
    for (int s = 0; s < 16; ++s) m = fmaxf(m, gp[((b * 16 + s) << 8) + c]);
    g[(b << 8) + c] = m;
}

// ---------------- cvec[b,o] = b3[o] + sum_c w3[o,256+c]*g[b,c] (fp32) ----------------
__global__ __launch_bounds__(256) void cvec_k(const float* __restrict__ w3,
                                              const float* __restrict__ b3,
                                              const float* __restrict__ g,
                                              float* __restrict__ cvec) {
    int idx = blockIdx.x * 256 + threadIdx.x;
    int b = idx >> 9, o = idx & 511;
    const float* gb = g + (b << 8);
    const float* wr = w3 + (long)o * 512 + 256;
    float s = b3[o];
    for (int c = 0; c < 256; ++c) s = fmaf(wr[c], gb[c], s);
    cvec[idx] = s;
}

// ---------------- softmax rows: E fp32 -> Abf bf16 ----------------
__global__ __launch_bounds__(256) void softmax_k(const float* __restrict__ E,
                                                 short* __restrict__ Ab) {
    long base = (long)blockIdx.y * GN * GN + (long)blockIdx.x * GN;
    const float* row = E + base;
    short* ob = Ab + base;
    const int tid = threadIdx.x;
    float v[8];
    float m = -1e30f;
#pragma unroll
    for (int i = 0; i < 8; ++i) {
        v[i] = row[tid + (i << 8)];
        m = fmaxf(m, v[i]);
    }
    m = block_max(m);
    float s = 0.f;
#pragma unroll
    for (int i = 0; i < 8; ++i) {
        v[i] = __expf(v[i] - m);
        s += v[i];
    }
    s = block_sum(s);
    float inv = 1.f / s;
#pragma unroll
    for (int i = 0; i < 8; ++i) ob[tid + (i << 8)] = f2bf(v[i] * inv);
}

// ---------------- column sums over q (two-stage) ----------------
__global__ __launch_bounds__(256) void colsum1_k(const short* __restrict__ Ab,
                                                 float* __restrict__ cp) {
    int kb = blockIdx.x, qs = blockIdx.y, z = blockIdx.z;
    int k = kb * 256 + threadIdx.x;
    const short* p = Ab + (long)z * GN * GN + (long)qs * 64 * GN + k;
    float s = 0.f;
    for (int qq = 0; qq < 64; ++qq) s += bf2f(p[(long)qq * GN]);
    cp[((z * 32 + qs) * GN) + k] = s;
}
__global__ __launch_bounds__(256) void colsum2_k(const float* __restrict__ cp,
                                                 float* __restrict__ cs) {
    int k = blockIdx.x * 256 + threadIdx.x, z = blockIdx.y;
    float s = 1e-9f;
    for (int qs = 0; qs < 32; ++qs) s += cp[((z * 32 + qs) * GN) + k];
    cs[z * GN + k] = s;
}

// ---------------- xvc[:, group cols] /= cs  (in place; folds L1 renorm into xv) ----------------
__global__ __launch_bounds__(256) void xvscale_k(short* __restrict__ xvc,
                                                 const float* __restrict__ cs,
                                                 int gix) {
    int idx = (blockIdx.x * 256 + threadIdx.x) * 4;  // over 512*8192
    int c = idx >> 13, j = idx & 8191;
    short* p = xvc + (long)c * 32768 + gix * 8192 + j;
    float4 cv = *(const float4*)(cs + j);
    uint2 u = *(const uint2*)p;
    short* sp = (short*)&u;
    sp[0] = f2bf(bf2f(sp[0]) / cv.x);
    sp[1] = f2bf(bf2f(sp[1]) / cv.y);
    sp[2] = f2bf(bf2f(sp[2]) / cv.z);
    sp[3] = f2bf(bf2f(sp[3]) / cv.w);
    *(uint2*)p = u;
}

// ---------------- BN stats two-stage on dT fp32 [32768,512] ----------------
__global__ __launch_bounds__(256) void bn1_k(const float* __restrict__ d,
                                             float* __restrict__ bs1,
                                             float* __restrict__ bs2) {
    int s = blockIdx.x, t = threadIdx.x;
    const float* p = d + (long)s * 256 * 512;
    float s0 = 0.f, q0 = 0.f, s1 = 0.f, q1 = 0.f;
    for (int rr = 0; rr < 256; ++rr) {
        float v0 = p[(long)rr * 512 + t];
        float v1 = p[(long)rr * 512 + t + 256];
        s0 += v0; q0 = fmaf(v0, v0, q0);
        s1 += v1; q1 = fmaf(v1, v1, q1);
    }
    bs1[s * 512 + t] = s0; bs1[s * 512 + t + 256] = s1;
    bs2[s * 512 + t] = q0; bs2[s * 512 + t + 256] = q1;
}
__global__ __launch_bounds__(256) void bn2_k(const float* __restrict__ bs1,
                                             const float* __restrict__ bs2,
                                             const float* __restrict__ gamma,
                                             const float* __restrict__ beta,
                                             float* __restrict__ sc,
                                             float* __restrict__ sh) {
    int c = blockIdx.x * 256 + threadIdx.x;
    float s = 0.f, s2 = 0.f;
    for (int i = 0; i < 128; ++i) {
        s += bs1[i * 512 + c];
        s2 += bs2[i * 512 + c];
    }
    const float cnt = (float)(GB * GN);
    float mu = s / cnt;
    float var = s2 / cnt - mu * mu;
    float r = rsqrtf(var + 1e-5f);
    float gm = gamma[c] * r;
    sc[c] = gm;
    sh[c] = beta[c] - gm * mu;
}

// ---------------- h4T = bf16(h3f + relu(d*sc+sh)) ----------------
__global__ __launch_bounds__(256) void bn_apply_k(const float* __restrict__ h3f,
                                                  const float* __restrict__ d,
                                                  const float* __restrict__ sc,
                                                  const float* __restrict__ sh,
                                                  short* __restrict__ h4) {
    long bidx = ((long)blockIdx.x * 256 + threadIdx.x) * 4;
    int c = (int)(bidx & 511);
    float4 d4 = *(const float4*)(d + bidx);
    float4 h4v = *(const float4*)(h3f + bidx);
    float4 a4 = *(const float4*)(sc + c);
    float4 b4 = *(const float4*)(sh + c);
    float r0 = h4v.x + fmaxf(fmaf(d4.x, a4.x, b4.x), 0.f);
    float r1 = h4v.y + fmaxf(fmaf(d4.y, a4.y, b4.y), 0.f);
    float r2 = h4v.z + fmaxf(fmaf(d4.z, a4.z, b4.z), 0.f);
    float r3 = h4v.w + fmaxf(fmaf(d4.w, a4.w, b4.w), 0.f);
    uint2 o;
    o.x = (unsigned short)f2bf(r0) | ((unsigned)(unsigned short)f2bf(r1) << 16);
    o.y = (unsigned short)f2bf(r2) | ((unsigned)(unsigned short)f2bf(r3) << 16);
    *(uint2*)(h4 + bidx) = o;
}

// ---------------- out[i] = max over 32 partials ----------------
__global__ __launch_bounds__(256) void max_final_k(const float* __restrict__ P,
                                                   float* __restrict__ out) {
    int i = blockIdx.x * 256 + threadIdx.x;
    const float* p = P + ((long)i << 5);
    float m = p[0];
#pragma unroll
    for (int j = 1; j < 32; ++j) m = fmaxf(m, p[j]);
    out[i] = m;
}

extern "C" void kernel_launch(void* const* d_in, const int* in_sizes, int n_in,
                              void* d_out, int out_size, void* d_ws, size_t ws_size,
                              hipStream_t stream) {
    const float* x = (const float*)d_in[0];
    const float* w1 = (const float*)d_in[1];
    const float* b1 = (const float*)d_in[2];
    const float* w2 = (const float*)d_in[3];
    const float* b2 = (const float*)d_in[4];
    const float* w3 = (const float*)d_in[5];
    const float* b3 = (const float*)d_in[6];
    const float* w4 = (const float*)d_in[7];
    const float* b4 = (const float*)d_in[8];
    const float* wqk = (const float*)d_in[9];
    const float* wv = (const float*)d_in[10];
    const float* bv = (const float*)d_in[11];
    const float* wt = (const float*)d_in[12];
    const float* bt = (const float*)d_in[13];
    const float* gamma = (const float*)d_in[14];
    const float* beta = (const float*)d_in[15];
    float* out = (float*)d_out;

    // ---- workspace carve (bytes), peak ~238.5 MiB ----
    char* base = (char*)d_ws;
    float* h3f = (float*)base;                    // [32768,512] f32  64 MB
    short* h3b = (short*)(base + 67108864);       // [32768,512] bf16 32 MB
    short* hsT = h3b;                             // alias (h3b dead after xv GEMM)
    short* kT = (short*)(base + 100663296);       // [32768,128] bf16  8 MB
    short* xvc = (short*)(base + 109051904);      // [512,32768] bf16 32 MB (channel-major)
    char* R1 = base + 142606336;                  // 64 MB region
    short* h1T = (short*)R1;                      //   [32768,128] bf16 (early)
    short* h2T = (short*)(R1 + 8388608);          //   [32768,256] bf16 (early)
    float* E = (float*)R1;                        //   [4,2048,2048] f32 (attn groups)
    float* dT = (float*)R1;                       //   [32768,512] f32 (late)
    char* R2 = base + 209715200;                  // 32 MB region
    short* Abf = (short*)R2;                      //   [4,2048,2048] bf16 (attn groups)
    short* h4T = (short*)R2;                      //   [32768,512] bf16 (late)
    char* S = base + 243269632;
    float* gp = (float*)S;                        // 262144
    float* g = (float*)(S + 262144);              // 16384
    float* cvec = (float*)(S + 278528);           // 32768
    float* cp = (float*)(S + 311296);             // 1048576
    float* cs = (float*)(S + 1359872);            // 32768
    float* bs1 = (float*)(S + 1392640);           // 262144
    float* bs2 = (float*)(S + 1654784);           // 262144
    float* bnsc = (float*)(S + 1916928);          // 2048
    float* bnsh = (float*)(S + 1918976);          // 2048
    float* Pmax = (float*)(S + 1921024);          // [16,1024,32] f32 = 2 MB
    short* w2b = (short*)(S + 4018176);
    short* w3b = (short*)(S + 4083712);
    short* wqkb = (short*)(S + 4608000);
    short* wvb = (short*)(S + 4739072);
    short* wtb = (short*)(S + 5263360);
    short* w4b = (short*)(S + 5787648);

    // 0. weight converts to bf16
    f2b_k<<<128, 256, 0, stream>>>(w2, w2b, 256 * 128);
    f2b_k<<<1024, 256, 0, stream>>>(w3, w3b, 512 * 512);
    f2b_k<<<256, 256, 0, stream>>>(wqk, wqkb, 128 * 512);
    f2b_k<<<1024, 256, 0, stream>>>(wv, wvb, 512 * 512);
    f2b_k<<<1024, 256, 0, stream>>>(wt, wtb, 512 * 512);
    f2b_k<<<2048, 256, 0, stream>>>(w4, w4b, 1024 * 512);

    // 1. posenc + conv1 + relu -> h1T
    posenc_conv1_k<<<128, 256, 0, stream>>>(x, w1, b1, h1T);

    // 2. h2T = h1T @ w2^T + b2  (no relu)   grid: (rowTiles, colTiles)
    mm_k<2, 1, false><<<dim3(256, 2, 1), 256, 0, stream>>>(
        h1T, 128, 0, w2b, 128, 0, b2, 0, nullptr, 0,
        nullptr, 0, h2T, 0, nullptr, 256, 128);

    // 3. g[b,c] = max_n h2T
    maxn1_k<<<dim3(GB, 16), 256, 0, stream>>>(h2T, gp);
    maxn2_k<<<GB, 256, 0, stream>>>(gp, g);

    // 4. cvec = w3[:,256:] @ g + b3 (fp32)
    cvec_k<<<32, 256, 0, stream>>>(w3, b3, g, cvec);

    // 5. h3 = relu(h2T @ w3[:,:256]^T + cvec)  -> fp32 + bf16
    mm_k<3, 3, true><<<dim3(256, 4, 1), 256, 0, stream>>>(
        h2T, 256, 0, w3b, 512, 0, cvec, 512, nullptr, 0,
        h3f, 0, h3b, 0, nullptr, 512, 256);

    // 6. kT = h3b @ wqk^T
    mm_k<2, 0, false><<<dim3(256, 1, 1), 256, 0, stream>>>(
        h3b, 512, 0, wqkb, 512, 0, nullptr, 0, nullptr, 0,
        nullptr, 0, kT, 0, nullptr, 128, 512);

    // 7. xv channel-major: D[c, point] = wv @ h3 + bv(row)
    mm_k<2, 2, false><<<dim3(4, 256, 1), 256, 0, stream>>>(
        wvb, 512, 0, h3b, 512, 0, bv, 0, nullptr, 0,
        nullptr, 0, xvc, 0, nullptr, 32768, 512);

    // 8. attention in groups of 4 batches
    for (int gix = 0; gix < 4; ++gix) {
        const short* kg = kT + (long)gix * 4 * GN * 128;
        // energy = kT kT^T (per batch in group)
        mm_k<1, 0, false><<<dim3(16, 16, 4), 256, 0, stream>>>(
            kg, 128, (long long)GN * 128, kg, 128, (long long)GN * 128,
            nullptr, 0, nullptr, 0, E, (long long)GN * GN, nullptr, 0,
            nullptr, GN, 128);
        softmax_k<<<dim3(GN, 4), 256, 0, stream>>>(E, Abf);
        colsum1_k<<<dim3(8, 32, 4), 256, 0, stream>>>(Abf, cp);
        colsum2_k<<<dim3(8, 4), 256, 0, stream>>>(cp, cs);
        // fold L1 renorm into xv group slice (in place)
        xvscale_k<<<4096, 256, 0, stream>>>(xvc, cs, gix);
        // xr (fused): hsT = bf16(h3f - attn @ xv^T)
        mm_k<4, 0, false><<<dim3(16, 4, 4), 256, 0, stream>>>(
            Abf, GN, (long long)GN * GN,
            xvc + (long)gix * 4 * GN, 32768, (long long)GN,
            nullptr, 0,
            h3f + (long)gix * 4 * GN * 512, (long long)GN * 512,
            nullptr, 0,
            hsT + (long)gix * 4 * GN * 512, (long long)GN * 512,
            nullptr, 512, GN);
    }

    // 9. dT = hsT @ wt^T + bt (fp32)
    mm_k<1, 1, false><<<dim3(256, 4, 1), 256, 0, stream>>>(
        hsT, 512, 0, wtb, 512, 0, bt, 0, nullptr, 0,
        dT, 0, nullptr, 0, nullptr, 512, 512);

    // 10. BN stats
    bn1_k<<<128, 256, 0, stream>>>(dT, bs1, bs2);
    bn2_k<<<2, 256, 0, stream>>>(bs1, bs2, gamma, beta, bnsc, bnsh);

    // 11. h4T = bf16(h3f + relu(bn(dT)))
    bn_apply_k<<<16384, 256, 0, stream>>>(h3f, dT, bnsc, bnsh, h4T);

    // 12. fused final conv + per-wave-tile col max -> Pmax [16,1024,32]
    mm_k<5, 1, false><<<dim3(256, 8, 1), 256, 0, stream>>>(
        h4T, 512, 0, w4b, 512, 0, b4, 0, nullptr, 0,
        nullptr, 0, nullptr, 0, Pmax, 1024, 512);

    // 13. out = max over tiles
    max_final_k<<<64, 256, 0, stream>>>(Pmax, out);
}